// Round 4
// baseline (587.118 us; speedup 1.0000x reference)
//
#include <hip/hip_runtime.h>
#include <hip/hip_bf16.h>
#include <math.h>

#define B_ 8
#define D_ 60
#define N_ 1024
#define K_ 20
#define P1_ 8192      // B*N
#define P2_ 163840    // B*N*K

typedef __attribute__((ext_vector_type(8))) short bf16x8;
typedef __attribute__((ext_vector_type(4))) short bf16x4;
typedef __attribute__((ext_vector_type(4))) float f32x4;

__device__ inline float b2f(short s) { return __uint_as_float(((unsigned)(unsigned short)s) << 16); }
__device__ inline short f2b(float f) { __hip_bfloat16 h = __float2bfloat16(f); return *(short*)&h; }
// order-preserving float<->uint key (for atomicMax on float values)
__device__ inline unsigned fenc(float f) { unsigned b = __float_as_uint(f); return (b & 0x80000000u) ? ~b : (b | 0x80000000u); }
__device__ inline float fdec(unsigned k) { return __uint_as_float((k & 0x80000000u) ? (k ^ 0x80000000u) : ~k); }

// ---- workspace layout (bytes), all 256-aligned ----
#define OFF_IDX   0ull          // int[P1][20] = 655360
#define OFF_XX    655360ull     // float[P1]
#define OFF_STATS 688128ull     // A[1792], B[1792], buv[128]
#define OFF_XT    720896ull     // bf16[P1][64] = 1MB
#define OFF_WB    1769472ull    // bf16 weights (wuv at WO1)
#define OFF_XC    2662400ull    // bf16[P1][512] = 8MB
#define OFF_H5    11051008ull   // bf16[P1][256] = 4MB
#define OFF_H6    15245312ull   // bf16[P1][1024] = 16MB
#define OFF_UV    32022528ull   // fp32[P1][128] = 4MB  (U | V)
#define OFF_XR1   36216832ull   // fp32[P1][64] = 2MB   raw max layer1
#define OFF_XR2   38313984ull   // uint[P1][64] = 2MB   ordered-key max layer2
#define OFF_XR3   40411136ull   // uint[P1][128] = 4MB
#define OFF_XR4   44605440ull   // uint[P1][256] = 8MB
#define OFF_H1    52994048ull   // bf16[P2][64] = 20MB
#define OFF_H2    73965568ull   // bf16[P2][64] = 20MB
#define OFF_H3    94937088ull   // bf16[P2][128] = 40MB ; pd (33.5MB fp32) aliases here
#define OFF_PART  136880128ull  // float partial stats, max 4*5120*128*4 = 10.5MB
#define OFF_PART2 149463040ull  // float stage-2 partials, 64KB
// end ~149.6 MiB

#define WO1 0
#define WO2 8192
#define WO3 12288
#define WO4 20480
#define WO5 53248
#define WO6 184320

#define SO1 0
#define SO2 64
#define SO3 128
#define SO4 256
#define SO5 512
#define SO6 768
#define NCH_TOT 1792

// ---------------- xx[bn] = sum_d x^2 ----------------
__global__ __launch_bounds__(256) void k_xx(const float* __restrict__ x,
                                            float* __restrict__ xx) {
  int bn = blockIdx.x * 256 + threadIdx.x;
  int b = bn >> 10, n = bn & 1023;
  const float* xb = x + (size_t)b * D_ * N_ + n;
  float s = 0.f;
  for (int d = 0; d < D_; ++d) { float v = xb[(size_t)d * N_]; s += v * v; }
  xx[bn] = s;
}

// ---------------- pd[b][n][m] = 2*dot - xx_n - xx_m ; tiled fp32 ----------------
__global__ __launch_bounds__(256) void k_pd(const float* __restrict__ x,
                                            const float* __restrict__ xx,
                                            float* __restrict__ pd) {
  __shared__ float lnn[D_][64];
  __shared__ float lmm[D_][128];
  int tid = threadIdx.x;
  int m0 = blockIdx.x * 128, n0 = blockIdx.y * 64, b = blockIdx.z;
  const float* xb = x + (size_t)b * D_ * N_;
  #pragma unroll
  for (int i = 0; i < 15; ++i) {
    int idx = tid + i * 256;
    int d = idx >> 6, col = idx & 63;
    lnn[d][col] = xb[(size_t)d * N_ + n0 + col];
  }
  #pragma unroll
  for (int i = 0; i < 30; ++i) {
    int idx = tid + i * 256;
    int d = idx >> 7, col = idx & 127;
    lmm[d][col] = xb[(size_t)d * N_ + m0 + col];
  }
  __syncthreads();
  int tn = tid >> 5, tm = tid & 31;
  float acc[8][4];
  #pragma unroll
  for (int i = 0; i < 8; ++i)
    #pragma unroll
    for (int j = 0; j < 4; ++j) acc[i][j] = 0.f;
  for (int d = 0; d < D_; ++d) {
    f32x4 mv  = *(const f32x4*)&lmm[d][tm * 4];
    f32x4 nva = *(const f32x4*)&lnn[d][tn * 8];
    f32x4 nvb = *(const f32x4*)&lnn[d][tn * 8 + 4];
    #pragma unroll
    for (int i = 0; i < 4; ++i)
      #pragma unroll
      for (int j = 0; j < 4; ++j) {
        acc[i][j]     = fmaf(nva[i], mv[j], acc[i][j]);
        acc[4 + i][j] = fmaf(nvb[i], mv[j], acc[4 + i][j]);
      }
  }
  const float* xxb = xx + b * 1024;
  f32x4 xxm = *(const f32x4*)(xxb + m0 + tm * 4);
  #pragma unroll
  for (int i = 0; i < 8; ++i) {
    int n = n0 + tn * 8 + i;
    float xxn = xxb[n];
    f32x4 o;
    #pragma unroll
    for (int j = 0; j < 4; ++j) o[j] = 2.f * acc[i][j] - xxn - xxm[j];
    *(f32x4*)(pd + ((size_t)(b * 1024 + n) * 1024) + m0 + tm * 4) = o;
  }
}

// ---------------- selection: one wave per point, top-20 ----------------
__global__ __launch_bounds__(256) void k_sel(const float* __restrict__ pd,
                                             int* __restrict__ idxb) {
  int tid = threadIdx.x;
  int wave = tid >> 6, lane = tid & 63;
  int bn = blockIdx.x * 4 + wave;
  const float* row = pd + (size_t)bn * 1024;
  int mbase = lane * 16;
  f32x4 r0 = *(const f32x4*)(row + mbase);
  f32x4 r1 = *(const f32x4*)(row + mbase + 4);
  f32x4 r2 = *(const f32x4*)(row + mbase + 8);
  f32x4 r3 = *(const f32x4*)(row + mbase + 12);
  float v[16];
  #pragma unroll
  for (int j = 0; j < 4; ++j) { v[j] = r0[j]; v[4 + j] = r1[j]; v[8 + j] = r2[j]; v[12 + j] = r3[j]; }
  int* outp = idxb + (size_t)bn * K_;
  for (int kk = 0; kk < K_; ++kk) {
    float bv = v[0]; int bj = 0;
    #pragma unroll
    for (int j = 1; j < 16; ++j)
      if (v[j] > bv) { bv = v[j]; bj = j; }
    int bi = mbase + bj;
    #pragma unroll
    for (int off = 1; off < 64; off <<= 1) {
      float ov = __shfl_xor(bv, off);
      int   oi = __shfl_xor(bi, off);
      if (ov > bv || (ov == bv && oi < bi)) { bv = ov; bi = oi; }
    }
    if (lane == 0) outp[kk] = bi;
    #pragma unroll
    for (int j = 0; j < 16; ++j)
      if (bi == mbase + j) v[j] = -INFINITY;
  }
}

// ---------------- xt: [B][60][N] fp32 -> [P1][64] bf16 (pad 4 zeros) ----------------
__global__ __launch_bounds__(256) void k_xt(const float* __restrict__ x,
                                            short* __restrict__ xt) {
  int bn = blockIdx.x * 256 + threadIdx.x;
  int b = bn >> 10, n = bn & 1023;
  const float* xb = x + (size_t)b * D_ * N_ + n;
  short* row = xt + (size_t)bn * 64;
  for (int c = 0; c < 60; ++c) row[c] = f2b(xb[(size_t)c * N_]);
  row[60] = 0; row[61] = 0; row[62] = 0; row[63] = 0;
}

// ---------------- wuv: rows 0..63 = W1a (nbr-ctr part), 64..127 = W1b - W1a ----------------
__global__ __launch_bounds__(256) void k_wuv(const float* __restrict__ w1,
                                             const float* __restrict__ b1,
                                             short* __restrict__ wuv,
                                             float* __restrict__ buv) {
  int t = blockIdx.x * 256 + threadIdx.x;  // 8192
  int o = t >> 6, c = t & 63;
  float v = 0.f;
  if (o < 64) { if (c < 60) v = w1[o * 120 + c]; }
  else { int o2 = o - 64; if (c < 60) v = w1[o2 * 120 + 60 + c] - w1[o2 * 120 + c]; }
  wuv[t] = f2b(v);
  if (t < 128) buv[t] = (t < 64) ? 0.f : b1[t - 64];
}

// ---------------- convert w2..w6 fp32 -> bf16 ----------------
__global__ __launch_bounds__(256) void k_wcvt(const float* __restrict__ w2,
                                              const float* __restrict__ w3,
                                              const float* __restrict__ w4,
                                              const float* __restrict__ w5,
                                              const float* __restrict__ w6,
                                              short* __restrict__ wbase) {
  int t = blockIdx.x * 256 + threadIdx.x;
  if (t < 4096) wbase[WO2 + t] = f2b(w2[t]);
  else if (t < 12288) wbase[WO3 + (t - 4096)] = f2b(w3[t - 4096]);
  else if (t < 45056) wbase[WO4 + (t - 12288)] = f2b(w4[t - 12288]);
  else if (t < 176128) wbase[WO5 + (t - 45056)] = f2b(w5[t - 45056]);
  else if (t < 438272) wbase[WO6 + (t - 176128)] = f2b(w6[t - 176128]);
}

// ---------------- standalone BN+lrelu, in place on bf16 [rows][C] ----------------
template <int C>
__global__ __launch_bounds__(256) void k_act(short* __restrict__ h,
                                             const float* __restrict__ A,
                                             const float* __restrict__ Bp) {
  int t = blockIdx.x * 256 + threadIdx.x;
  int c0 = (t & (C / 8 - 1)) * 8;
  bf16x8 v = *(bf16x8*)(h + (size_t)t * 8);
  f32x4 a0 = *(const f32x4*)(A + c0), a1 = *(const f32x4*)(A + c0 + 4);
  f32x4 b0 = *(const f32x4*)(Bp + c0), b1 = *(const f32x4*)(Bp + c0 + 4);
  #pragma unroll
  for (int j = 0; j < 8; ++j) {
    float aj = j < 4 ? a0[j] : a1[j - 4];
    float bj = j < 4 ? b0[j] : b1[j - 4];
    float f = b2f(v[j]) * aj + bj;
    f = f >= 0.f ? f : 0.2f * f;
    v[j] = f2b(f);
  }
  *(bf16x8*)(h + (size_t)t * 8) = v;
}

// ---------------- pipelined multi-iteration MFMA GEMM ----------------
// Block = 128 rows x 64 co per iteration; iterations sweep (row-panel NR) x
// (co-chunk NCO) x (k-panel NKP) with depth-1 register prefetch (T14):
// next stage's global loads issue during current compute; ds_write after barrier.
// Epilogue is barrier-free: stats via shfl + per-wave part rows; max-over-k via
// segmented shfl-max (leaders atomicMax). WMAX relies on BN+lrelu monotonicity.
template <int K, int COUT, int NR, int NCO, bool APPLY, bool STATS, bool WMAX, bool HSTORE, bool F32OUT>
__global__ __launch_bounds__(256) void k_gemm(const short* __restrict__ in,
                                              const short* __restrict__ wb,
                                              const float* __restrict__ bias,
                                              const float* __restrict__ Ain,
                                              const float* __restrict__ Bin,
                                              float* __restrict__ part,
                                              short* __restrict__ out,
                                              unsigned* __restrict__ umax) {
  constexpr int NKP = (K > 128) ? (K / 64) : 1;   // staged k-panels
  constexpr int KA  = (K > 128) ? 64 : K;         // staged chunk width
  constexpr int PKA = KA + 8;
  constexpr int PKW = KA + 8;
  constexpr bool W_RES = (NKP == 1) && (NCO <= 2);
  constexpr int WROWS = W_RES ? NCO * 64 : 64;
  constexpr int NIT = NR * NCO * NKP;
  constexpr int ACPR = KA / 8;                    // 16B chunks per row
  constexpr int ACSH = (ACPR == 16) ? 4 : 3;
  constexpr int ALOADS = (128 * KA) / (256 * 8);
  constexpr int WLOADS = (WROWS * KA) / (256 * 8);
  constexpr int NSTEP = (W_RES && NCO == 2) ? 2 : 1;  // iterations per stage event
  constexpr int KS = KA / 32;

  __shared__ short ldsA[128 * PKA];
  __shared__ short ldsW[WROWS * PKW];

  int tid = threadIdx.x;
  int w = tid >> 6, lane = tid & 63;
  int ln = lane & 15, quad = lane >> 4;
  // XCD-bijective swizzle (block counts are multiples of 8)
  int bid = blockIdx.y * gridDim.x + blockIdx.x;
  int tot = gridDim.x * gridDim.y;
  int gid = (bid & 7) * (tot >> 3) + (bid >> 3);
  int bxx = gid % gridDim.x;
  int rp = gid / gridDim.x;

  auto stgA = [](int i2) { return (NKP > 1) || ((i2 % (NCO > 0 ? NCO : 1)) == 0); };
  auto stgW = [](int i2) { return !W_RES || i2 == 0; };

  auto issueA = [&](int i2, bf16x8* dst) {
    const int r_ = i2 / (NCO * NKP), kp_ = i2 % NKP;
    const short* src = in + (size_t)((rp * NR + r_) * 128) * K + kp_ * 64;
    #pragma unroll
    for (int l = 0; l < ALOADS; ++l) {
      int gI = l * 256 + tid, rowI = gI >> ACSH, cI = gI & (ACPR - 1);
      dst[l] = *(const bf16x8*)(src + (size_t)rowI * K + cI * 8);
    }
  };
  auto issueW = [&](int i2, bf16x8* dst) {
    const int kp_ = i2 % NKP, co_ = (i2 / NKP) % NCO;
    const short* src = wb + (size_t)(bxx * NCO * 64 + (W_RES ? 0 : co_ * 64)) * K + kp_ * 64;
    #pragma unroll
    for (int l = 0; l < WLOADS; ++l) {
      int gI = l * 256 + tid, rowI = gI >> ACSH, cI = gI & (ACPR - 1);
      dst[l] = *(const bf16x8*)(src + (size_t)rowI * K + cI * 8);
    }
  };
  auto writeA = [&](int i2, bf16x8* srcR) {
    const int kp_ = i2 % NKP;
    #pragma unroll
    for (int l = 0; l < ALOADS; ++l) {
      int gI = l * 256 + tid, rowI = gI >> ACSH, cI = gI & (ACPR - 1);
      bf16x8 v = srcR[l];
      if (APPLY) {
        int kc = kp_ * 64 + cI * 8;
        f32x4 a0 = *(const f32x4*)(Ain + kc), a1 = *(const f32x4*)(Ain + kc + 4);
        f32x4 b0 = *(const f32x4*)(Bin + kc), b1 = *(const f32x4*)(Bin + kc + 4);
        #pragma unroll
        for (int jj = 0; jj < 8; ++jj) {
          float aj = jj < 4 ? a0[jj] : a1[jj - 4];
          float bj = jj < 4 ? b0[jj] : b1[jj - 4];
          float f = b2f(v[jj]) * aj + bj;
          f = f >= 0.f ? f : 0.2f * f;
          v[jj] = f2b(f);
        }
      }
      *(bf16x8*)(ldsA + rowI * PKA + cI * 8) = v;
    }
  };
  auto writeW = [&](bf16x8* srcR) {
    #pragma unroll
    for (int l = 0; l < WLOADS; ++l) {
      int gI = l * 256 + tid, rowI = gI >> ACSH, cI = gI & (ACPR - 1);
      *(bf16x8*)(ldsW + rowI * PKW + cI * 8) = srcR[l];
    }
  };

  bf16x8 rAa[ALOADS], rAb[ALOADS], rWa[WLOADS], rWb[WLOADS];
  // prologue: stage event 0 directly, prefetch event 1
  issueA(0, rAa);
  issueW(0, rWa);
  writeA(0, rAa);
  writeW(rWa);
  if (NSTEP < NIT) {
    if (stgA(NSTEP)) issueA(NSTEP, rAb);
    if (stgW(NSTEP)) issueW(NSTEP, rWb);
  }
  __syncthreads();

  f32x4 acc[4][2];
  #pragma unroll
  for (int i = 0; i < NIT; ++i) {
    if (i && (i % NSTEP) == 0) {
      const int e = i / NSTEP;
      __syncthreads();
      if (stgA(i)) writeA(i, (e & 1) ? rAb : rAa);
      if (stgW(i)) writeW((e & 1) ? rWb : rWa);
      if (i + NSTEP < NIT) {
        if (stgA(i + NSTEP)) issueA(i + NSTEP, (e & 1) ? rAa : rAb);
        if (stgW(i + NSTEP)) issueW(i + NSTEP, (e & 1) ? rWa : rWb);
      }
      __syncthreads();
    }
    if ((i % NKP) == 0) {
      #pragma unroll
      for (int m = 0; m < 4; ++m)
        #pragma unroll
        for (int t = 0; t < 2; ++t) acc[m][t] = (f32x4){0.f, 0.f, 0.f, 0.f};
    }
    // compute
    {
      const int wbase = W_RES ? (((i / NKP) % NCO) * 64) : 0;
      #pragma unroll
      for (int ks = 0; ks < KS; ++ks) {
        bf16x8 fw[4], fa[2];
        #pragma unroll
        for (int m = 0; m < 4; ++m)
          fw[m] = *(const bf16x8*)(ldsW + (wbase + m * 16 + ln) * PKW + ks * 32 + quad * 8);
        #pragma unroll
        for (int t = 0; t < 2; ++t)
          fa[t] = *(const bf16x8*)(ldsA + (w * 32 + t * 16 + ln) * PKA + ks * 32 + quad * 8);
        #pragma unroll
        for (int m = 0; m < 4; ++m)
          #pragma unroll
          for (int t = 0; t < 2; ++t)
            acc[m][t] = __builtin_amdgcn_mfma_f32_16x16x32_bf16(fw[m], fa[t], acc[m][t], 0, 0, 0);
      }
    }
    if ((i % NKP) == (NKP - 1)) {
      // finalize this (row-panel, co-chunk)
      const int r_  = i / (NCO * NKP);
      const int co_ = (i / NKP) % NCO;
      const int cog = bxx * NCO + co_;
      const int co0 = cog * 64;
      #pragma unroll
      for (int m = 0; m < 4; ++m) {
        f32x4 bs = *(const f32x4*)(bias + co0 + m * 16 + quad * 4);
        #pragma unroll
        for (int t = 0; t < 2; ++t)
          #pragma unroll
          for (int j = 0; j < 4; ++j) acc[m][t][j] += bs[j];
      }
      const int prow = (rp * NR + r_) * 128 + w * 32;
      if (HSTORE) {
        #pragma unroll
        for (int m = 0; m < 4; ++m)
          #pragma unroll
          for (int t = 0; t < 2; ++t) {
            int p = prow + t * 16 + ln;
            if (F32OUT) {
              *(f32x4*)((float*)out + (size_t)p * COUT + co0 + m * 16 + quad * 4) = acc[m][t];
            } else {
              bf16x4 o;
              #pragma unroll
              for (int jr = 0; jr < 4; ++jr) o[jr] = f2b(acc[m][t][jr]);
              *(bf16x4*)(out + (size_t)p * COUT + co0 + m * 16 + quad * 4) = o;
            }
          }
      }
      if (STATS) {
        size_t key = ((size_t)cog * (gridDim.y * NR) + (size_t)(rp * NR + r_)) * 4 + w;
        float* pp = part + key * 128;
        #pragma unroll
        for (int m = 0; m < 4; ++m)
          #pragma unroll
          for (int j = 0; j < 4; ++j) {
            float v0 = acc[m][0][j], v1 = acc[m][1][j];
            float s = v0 + v1, ss = v0 * v0 + v1 * v1;
            #pragma unroll
            for (int off = 1; off < 16; off <<= 1) {
              s += __shfl_xor(s, off); ss += __shfl_xor(ss, off);
            }
            if (ln == 0) {
              pp[m * 16 + quad * 4 + j] = s;
              pp[64 + m * 16 + quad * 4 + j] = ss;
            }
          }
      }
      if (WMAX) {
        #pragma unroll
        for (int t = 0; t < 2; ++t) {
          int row = prow + t * 16 + ln;
          int g = row / 20;
          bool lead = (ln == 0) || (row - g * 20 == 0);
          int og1 = __shfl_xor(g, 1), og2 = __shfl_xor(g, 2);
          int og4 = __shfl_xor(g, 4), og8 = __shfl_xor(g, 8);
          #pragma unroll
          for (int m = 0; m < 4; ++m)
            #pragma unroll
            for (int j = 0; j < 4; ++j) {
              float v = acc[m][t][j];
              float ov;
              ov = __shfl_xor(v, 1); if (og1 == g && ov > v) v = ov;
              ov = __shfl_xor(v, 2); if (og2 == g && ov > v) v = ov;
              ov = __shfl_xor(v, 4); if (og4 == g && ov > v) v = ov;
              ov = __shfl_xor(v, 8); if (og8 == g && ov > v) v = ov;
              if (lead) atomicMax(&umax[(size_t)g * COUT + co0 + m * 16 + quad * 4 + j], fenc(v));
            }
        }
      }
    }
  }
}

// ---------------- expand: h1[(n,k),c] = U[nbr,c] + V[n,c]; fused stats + max ----------------
__global__ __launch_bounds__(256) void k_expand(const float* __restrict__ UVf,
                                                const int* __restrict__ idxb,
                                                short* __restrict__ h1,
                                                float* __restrict__ xr1,
                                                float* __restrict__ part) {
  int tid = threadIdx.x;
  int lp = tid >> 4;
  int c0 = (tid & 15) * 4;
  int pt = blockIdx.x * 16 + lp;
  int base = (pt >> 10) << 10;
  f32x4 V = *(const f32x4*)(UVf + (size_t)pt * 128 + 64 + c0);
  f32x4 sum = (f32x4){0.f, 0.f, 0.f, 0.f};
  f32x4 ssq = (f32x4){0.f, 0.f, 0.f, 0.f};
  f32x4 mx = (f32x4){-INFINITY, -INFINITY, -INFINITY, -INFINITY};
  const int* ip = idxb + (size_t)pt * K_;
  size_t hb = (size_t)pt * K_ * 64 + c0;
  for (int k = 0; k < K_; ++k) {
    int nb = base + ip[k];
    f32x4 U = *(const f32x4*)(UVf + (size_t)nb * 128 + c0);
    bf16x4 o;
    #pragma unroll
    for (int j = 0; j < 4; ++j) {
      float h = U[j] + V[j];
      mx[j] = fmaxf(mx[j], U[j]);
      sum[j] += h; ssq[j] += h * h;
      o[j] = f2b(h);
    }
    *(bf16x4*)(h1 + hb + (size_t)k * 64) = o;
  }
  f32x4 xo;
  #pragma unroll
  for (int j = 0; j < 4; ++j) xo[j] = mx[j] + V[j];
  *(f32x4*)(xr1 + (size_t)pt * 64 + c0) = xo;
  __shared__ float ls[2048];
  *(f32x4*)(ls + tid * 4) = sum;
  *(f32x4*)(ls + 1024 + tid * 4) = ssq;
  __syncthreads();
  if (tid < 32) {
    int cl = tid & 15;
    bool issq = tid >= 16;
    const float* src = ls + (issq ? 1024 : 0);
    f32x4 s = (f32x4){0.f, 0.f, 0.f, 0.f};
    #pragma unroll
    for (int g = 0; g < 16; ++g) {
      f32x4 v = *(const f32x4*)(src + (g * 16 + cl) * 4);
      s[0] += v[0]; s[1] += v[1]; s[2] += v[2]; s[3] += v[3];
    }
    *(f32x4*)(part + (size_t)blockIdx.x * 128 + (issq ? 64 : 0) + cl * 4) = s;
  }
}

// ---------------- stage-1 reduction: part[cc][NB][128] -> part2[cc][32][128] ----------------
__global__ __launch_bounds__(256) void k_red(const float* __restrict__ part, int NB,
                                             float* __restrict__ part2) {
  int cc = blockIdx.x, by = blockIdx.y;
  int tid = threadIdx.x;
  int rg = tid >> 5;
  int c4 = (tid & 31) * 4;
  int chunk = NB >> 5;
  const float* p = part + ((size_t)cc * NB + (size_t)by * chunk) * 128;
  f32x4 acc = (f32x4){0.f, 0.f, 0.f, 0.f};
  for (int r = rg; r < chunk; r += 8) {
    f32x4 v = *(const f32x4*)(p + (size_t)r * 128 + c4);
    acc[0] += v[0]; acc[1] += v[1]; acc[2] += v[2]; acc[3] += v[3];
  }
  __shared__ float lds[1024];
  *(f32x4*)(lds + tid * 4) = acc;
  __syncthreads();
  if (tid < 32) {
    f32x4 s = (f32x4){0.f, 0.f, 0.f, 0.f};
    #pragma unroll
    for (int g = 0; g < 8; ++g) {
      f32x4 v = *(const f32x4*)(lds + (g * 32 + tid) * 4);
      s[0] += v[0]; s[1] += v[1]; s[2] += v[2]; s[3] += v[3];
    }
    *(f32x4*)(part2 + ((size_t)cc * 32 + by) * 128 + tid * 4) = s;
  }
}

// ---------------- reduce partials -> A = g*rsqrt(var+eps), B = be - mean*A ----------------
__global__ __launch_bounds__(256) void k_bnab(const float* __restrict__ part, int NB,
                                              const float* __restrict__ g,
                                              const float* __restrict__ be,
                                              float* __restrict__ A,
                                              float* __restrict__ Bp, float inv) {
  __shared__ float red[256];
  int tid = threadIdx.x;
  int j = tid & 127, h = tid >> 7;
  const float* p = part + (size_t)blockIdx.x * NB * 128;
  float s = 0.f;
  for (int bx = h; bx < NB; bx += 2) s += p[(size_t)bx * 128 + j];
  red[tid] = s;
  __syncthreads();
  if (tid < 128) red[tid] = red[tid] + red[tid + 128];
  __syncthreads();
  if (tid < 64) {
    int c = blockIdx.x * 64 + tid;
    float m = red[tid] * inv;
    float v = red[64 + tid] * inv - m * m;
    float a = g[c] * rsqrtf(v + 1e-5f);
    A[c] = a; Bp[c] = be[c] - m * a;
  }
}

// ---------------- xcat: decode raw maxes, apply BN+lrelu, pack [P1][512] bf16 ----------------
__global__ __launch_bounds__(256) void k_xcat(const float* __restrict__ xr1,
                                              const unsigned* __restrict__ xr2,
                                              const unsigned* __restrict__ xr3,
                                              const unsigned* __restrict__ xr4,
                                              const float* __restrict__ A,
                                              const float* __restrict__ Bp,
                                              short* __restrict__ xcat) {
  int t = blockIdx.x * 256 + threadIdx.x;  // P1*128
  int p = t >> 7, cq = t & 127;
  int c0 = cq * 4;
  f32x4 v;
  if (c0 < 64) {
    v = *(const f32x4*)(xr1 + (size_t)p * 64 + c0);
  } else {
    const unsigned* src; int cc;
    if (c0 < 128)      { src = xr2 + (size_t)p * 64;  cc = c0 - 64; }
    else if (c0 < 256) { src = xr3 + (size_t)p * 128; cc = c0 - 128; }
    else               { src = xr4 + (size_t)p * 256; cc = c0 - 256; }
    #pragma unroll
    for (int j = 0; j < 4; ++j) v[j] = fdec(src[cc + j]);
  }
  f32x4 a = *(const f32x4*)(A + c0);
  f32x4 b = *(const f32x4*)(Bp + c0);
  bf16x4 o;
  #pragma unroll
  for (int j = 0; j < 4; ++j) {
    float f = v[j] * a[j] + b[j];
    f = f >= 0.f ? f : 0.2f * f;
    o[j] = f2b(f);
  }
  *(bf16x4*)(xcat + (size_t)p * 512 + c0) = o;
}

// ---------------- final: BN+lrelu bf16 [P1][1024] -> fp32 out ----------------
__global__ __launch_bounds__(256) void k_apply_out(const short* __restrict__ h,
                                                   const float* __restrict__ A,
                                                   const float* __restrict__ Bp,
                                                   float* __restrict__ out) {
  int t = blockIdx.x * 256 + threadIdx.x;
  int c0 = (t & 255) * 4;
  f32x4 a = *(const f32x4*)(A + c0);
  f32x4 b = *(const f32x4*)(Bp + c0);
  bf16x4 v = *(const bf16x4*)(h + (size_t)t * 4);
  f32x4 o;
  #pragma unroll
  for (int r = 0; r < 4; ++r) {
    float f = b2f(v[r]) * a[r] + b[r];
    o[r] = f >= 0.f ? f : 0.2f * f;
  }
  *(f32x4*)(out + (size_t)t * 4) = o;
}

extern "C" void kernel_launch(void* const* d_in, const int* in_sizes, int n_in,
                              void* d_out, int out_size, void* d_ws, size_t ws_size,
                              hipStream_t stream) {
  const float* x   = (const float*)d_in[0];
  const float* w1  = (const float*)d_in[1];
  const float* b1  = (const float*)d_in[2];
  const float* g1  = (const float*)d_in[3];
  const float* be1 = (const float*)d_in[4];
  const float* w2  = (const float*)d_in[5];
  const float* b2  = (const float*)d_in[6];
  const float* g2  = (const float*)d_in[7];
  const float* be2 = (const float*)d_in[8];
  const float* w3  = (const float*)d_in[9];
  const float* b3  = (const float*)d_in[10];
  const float* g3  = (const float*)d_in[11];
  const float* be3 = (const float*)d_in[12];
  const float* w4  = (const float*)d_in[13];
  const float* b4  = (const float*)d_in[14];
  const float* g4  = (const float*)d_in[15];
  const float* be4 = (const float*)d_in[16];
  const float* w5  = (const float*)d_in[17];
  const float* b5  = (const float*)d_in[18];
  const float* g5  = (const float*)d_in[19];
  const float* be5 = (const float*)d_in[20];
  const float* w6  = (const float*)d_in[21];
  const float* b6  = (const float*)d_in[22];
  const float* g6  = (const float*)d_in[23];
  const float* be6 = (const float*)d_in[24];
  float* out = (float*)d_out;
  char* ws = (char*)d_ws;

  int*      idxb = (int*)(ws + OFF_IDX);
  float*    xx   = (float*)(ws + OFF_XX);
  float*    Aall = (float*)(ws + OFF_STATS);
  float*    Ball = Aall + NCH_TOT;
  float*    buv  = Ball + NCH_TOT;
  short*    xt   = (short*)(ws + OFF_XT);
  short*    wbb  = (short*)(ws + OFF_WB);
  short*    xcat = (short*)(ws + OFF_XC);
  short*    h5   = (short*)(ws + OFF_H5);
  short*    h6   = (short*)(ws + OFF_H6);
  float*    UVf  = (float*)(ws + OFF_UV);
  float*    xr1  = (float*)(ws + OFF_XR1);
  unsigned* xr2  = (unsigned*)(ws + OFF_XR2);
  unsigned* xr3  = (unsigned*)(ws + OFF_XR3);
  unsigned* xr4  = (unsigned*)(ws + OFF_XR4);
  short*    h1   = (short*)(ws + OFF_H1);
  short*    h2   = (short*)(ws + OFF_H2);
  short*    h3   = (short*)(ws + OFF_H3);
  float*    pd    = (float*)(ws + OFF_H3);   // aliases h3; consumed before h3 written
  float*    part  = (float*)(ws + OFF_PART);
  float*    part2 = (float*)(ws + OFF_PART2);

  // init ordered-key max buffers (key 0 < key(-inf))
  hipMemsetAsync(ws + OFF_XR2, 0, 2097152ull + 4194304ull + 8388608ull, stream);

  k_xx <<<P1_ / 256, 256, 0, stream>>>(x, xx);
  k_pd <<<dim3(8, 16, 8), 256, 0, stream>>>(x, xx, pd);
  k_sel<<<P1_ / 4, 256, 0, stream>>>(pd, idxb);
  k_xt <<<P1_ / 256, 256, 0, stream>>>(x, xt);
  k_wuv<<<32, 256, 0, stream>>>(w1, b1, wbb + WO1, buv);
  k_wcvt<<<1712, 256, 0, stream>>>(w2, w3, w4, w5, w6, wbb);

  // layer 1 factorized: UV[P1][128] fp32 = [W1a·x | (W1b-W1a)·x + b1]
  k_gemm<64, 128, 1, 1, false, false, false, true, true><<<dim3(2, 64), 256, 0, stream>>>(
      xt, wbb + WO1, buv, nullptr, nullptr, nullptr, (short*)UVf, nullptr);
  // expand: h1 = U[nbr]+V, fused stats partials + raw max -> xr1
  k_expand<<<P1_ / 16, 256, 0, stream>>>(UVf, idxb, h1, xr1, part);
  k_red <<<dim3(1, 32), 256, 0, stream>>>(part, P1_ / 16, part2);
  k_bnab<<<1, 256, 0, stream>>>(part2, 32, g1, be1, Aall + SO1, Ball + SO1, 1.f / P2_);

  // layer 2: act(h1) x w2 -> h2 + stats + raw max -> xr2 ; NR=2 pipelined
  k_gemm<64, 64, 2, 1, true, true, true, true, false><<<dim3(1, 640), 256, 0, stream>>>(
      h1, wbb + WO2, b2, Aall + SO1, Ball + SO1, part, h2, xr2);
  k_red <<<dim3(1, 32), 256, 0, stream>>>(part, 5120, part2);
  k_bnab<<<1, 256, 0, stream>>>(part2, 32, g2, be2, Aall + SO2, Ball + SO2, 1.f / P2_);

  // layer 3: act(h2) x w3 -> h3 + stats + raw max -> xr3 ; NR=2 x NCO=2, W resident
  k_gemm<64, 128, 2, 2, true, true, true, true, false><<<dim3(1, 640), 256, 0, stream>>>(
      h2, wbb + WO3, b3, Aall + SO2, Ball + SO2, part, h3, xr3);
  k_red <<<dim3(2, 32), 256, 0, stream>>>(part, 5120, part2);
  k_bnab<<<2, 256, 0, stream>>>(part2, 32, g3, be3, Aall + SO3, Ball + SO3, 1.f / P2_);

  // layer 4: act(h3) x w4 -> stats + raw max only; A resident, 4 co-chunks looped
  k_gemm<128, 256, 1, 4, true, true, true, false, false><<<dim3(1, 1280), 256, 0, stream>>>(
      h3, wbb + WO4, b4, Aall + SO3, Ball + SO3, part, nullptr, xr4);
  k_red <<<dim3(4, 32), 256, 0, stream>>>(part, 5120, part2);
  k_bnab<<<4, 256, 0, stream>>>(part2, 32, g4, be4, Aall + SO4, Ball + SO4, 1.f / P2_);

  // assemble xcat from raw maxes with BN+lrelu
  k_xcat<<<P1_ * 128 / 256, 256, 0, stream>>>(xr1, xr2, xr3, xr4, Aall, Ball, xcat);

  // layer 5: xcat x w5 -> h5 + stats ; 8 k-panels pipelined
  k_gemm<512, 256, 1, 1, false, true, false, true, false><<<dim3(4, 64), 256, 0, stream>>>(
      xcat, wbb + WO5, b5, nullptr, nullptr, part, h5, nullptr);
  k_bnab<<<4, 256, 0, stream>>>(part, 256, g5, be5, Aall + SO5, Ball + SO5, 1.f / P1_);

  // activate h5 once (tiny) so layer 6 stages without NX-duplicated apply
  k_act<256><<<P1_ * 256 / 2048, 256, 0, stream>>>(h5, Aall + SO5, Ball + SO5);

  // layer 6: act(h5) x w6 -> h6 + stats ; NR=2 x 4 k-panels pipelined
  k_gemm<256, 1024, 2, 1, false, true, false, true, false><<<dim3(16, 32), 256, 0, stream>>>(
      h5, wbb + WO6, b6, nullptr, nullptr, part, h6, nullptr);
  k_bnab<<<16, 256, 0, stream>>>(part, 256, g6, be6, Aall + SO6, Ball + SO6, 1.f / P1_);
  k_apply_out<<<P1_ * 256 / 256, 256, 0, stream>>>(h6, Aall + SO6, Ball + SO6, out);

  (void)in_sizes; (void)n_in; (void)out_size; (void)ws_size;
}

// Round 5
// 582.951 us; speedup vs baseline: 1.0071x; 1.0071x over previous
//
#include <hip/hip_runtime.h>
#include <hip/hip_bf16.h>
#include <math.h>

#define B_ 8
#define D_ 60
#define N_ 1024
#define K_ 20
#define P1_ 8192      // B*N
#define P2_ 163840    // B*N*K

typedef __attribute__((ext_vector_type(8))) short bf16x8;
typedef __attribute__((ext_vector_type(4))) short bf16x4;
typedef __attribute__((ext_vector_type(4))) float f32x4;

__device__ inline float b2f(short s) { return __uint_as_float(((unsigned)(unsigned short)s) << 16); }
__device__ inline short f2b(float f) { __hip_bfloat16 h = __float2bfloat16(f); return *(short*)&h; }
// order-preserving float<->uint key (for atomicMax on float values)
__device__ inline unsigned fenc(float f) { unsigned b = __float_as_uint(f); return (b & 0x80000000u) ? ~b : (b | 0x80000000u); }
__device__ inline float fdec(unsigned k) { return __uint_as_float((k & 0x80000000u) ? (k ^ 0x80000000u) : ~k); }

// async global->LDS, 16B per lane; lds dest = wave-uniform base + lane*16
__device__ __forceinline__ void gl16(const short* g, short* l) {
  __builtin_amdgcn_global_load_lds(
      (const __attribute__((address_space(1))) unsigned int*)g,
      (__attribute__((address_space(3))) unsigned int*)l, 16, 0, 0);
}

// ---- workspace layout (bytes), all 256-aligned ----
#define OFF_IDX   0ull          // int[P1][20] = 655360
#define OFF_XX    655360ull     // float[P1]
#define OFF_STATS 688128ull     // A[1792], B[1792], buv[128]
#define OFF_XT    720896ull     // bf16[P1][64] = 1MB
#define OFF_WB    1769472ull    // bf16 weights (wuv at WO1)
#define OFF_XC    2662400ull    // bf16[P1][512] = 8MB
#define OFF_H5    11051008ull   // bf16[P1][256] = 4MB
#define OFF_H6    15245312ull   // bf16[P1][1024] = 16MB
#define OFF_UV    32022528ull   // fp32[P1][128] = 4MB  (U | V)
#define OFF_XR1   36216832ull   // fp32[P1][64] = 2MB   raw max layer1
#define OFF_XR2   38313984ull   // uint[P1][64] = 2MB   ordered-key max layer2
#define OFF_XR3   40411136ull   // uint[P1][128] = 4MB
#define OFF_XR4   44605440ull   // uint[P1][256] = 8MB
#define OFF_H1    52994048ull   // bf16[P2][64] = 20MB
#define OFF_H2    73965568ull   // bf16[P2][64] = 20MB
#define OFF_H3    94937088ull   // bf16[P2][128] = 40MB ; pd (33.5MB fp32) aliases here
#define OFF_PART  136880128ull  // float partial stats, max 16*256*128*4 = 2.1MB (L6); L2/L3 2.6MB
#define OFF_PART2 149463040ull  // float stage-2 partials, 64KB
// end ~149.6 MiB

#define WO1 0
#define WO2 8192
#define WO3 12288
#define WO4 20480
#define WO5 53248
#define WO6 184320

#define SO1 0
#define SO2 64
#define SO3 128
#define SO4 256
#define SO5 512
#define SO6 768
#define NCH_TOT 1792

// ---------------- xx[bn] = sum_d x^2 ----------------
__global__ __launch_bounds__(256) void k_xx(const float* __restrict__ x,
                                            float* __restrict__ xx) {
  int bn = blockIdx.x * 256 + threadIdx.x;
  int b = bn >> 10, n = bn & 1023;
  const float* xb = x + (size_t)b * D_ * N_ + n;
  float s = 0.f;
  for (int d = 0; d < D_; ++d) { float v = xb[(size_t)d * N_]; s += v * v; }
  xx[bn] = s;
}

// ---------------- pd[b][n][m] = 2*dot - xx_n - xx_m ; tiled fp32 ----------------
__global__ __launch_bounds__(256) void k_pd(const float* __restrict__ x,
                                            const float* __restrict__ xx,
                                            float* __restrict__ pd) {
  __shared__ float lnn[D_][64];
  __shared__ float lmm[D_][128];
  int tid = threadIdx.x;
  int m0 = blockIdx.x * 128, n0 = blockIdx.y * 64, b = blockIdx.z;
  const float* xb = x + (size_t)b * D_ * N_;
  #pragma unroll
  for (int i = 0; i < 15; ++i) {
    int idx = tid + i * 256;
    int d = idx >> 6, col = idx & 63;
    lnn[d][col] = xb[(size_t)d * N_ + n0 + col];
  }
  #pragma unroll
  for (int i = 0; i < 30; ++i) {
    int idx = tid + i * 256;
    int d = idx >> 7, col = idx & 127;
    lmm[d][col] = xb[(size_t)d * N_ + m0 + col];
  }
  __syncthreads();
  int tn = tid >> 5, tm = tid & 31;
  float acc[8][4];
  #pragma unroll
  for (int i = 0; i < 8; ++i)
    #pragma unroll
    for (int j = 0; j < 4; ++j) acc[i][j] = 0.f;
  for (int d = 0; d < D_; ++d) {
    f32x4 mv  = *(const f32x4*)&lmm[d][tm * 4];
    f32x4 nva = *(const f32x4*)&lnn[d][tn * 8];
    f32x4 nvb = *(const f32x4*)&lnn[d][tn * 8 + 4];
    #pragma unroll
    for (int i = 0; i < 4; ++i)
      #pragma unroll
      for (int j = 0; j < 4; ++j) {
        acc[i][j]     = fmaf(nva[i], mv[j], acc[i][j]);
        acc[4 + i][j] = fmaf(nvb[i], mv[j], acc[4 + i][j]);
      }
  }
  const float* xxb = xx + b * 1024;
  f32x4 xxm = *(const f32x4*)(xxb + m0 + tm * 4);
  #pragma unroll
  for (int i = 0; i < 8; ++i) {
    int n = n0 + tn * 8 + i;
    float xxn = xxb[n];
    f32x4 o;
    #pragma unroll
    for (int j = 0; j < 4; ++j) o[j] = 2.f * acc[i][j] - xxn - xxm[j];
    *(f32x4*)(pd + ((size_t)(b * 1024 + n) * 1024) + m0 + tm * 4) = o;
  }
}

// ---------------- selection: one wave per point, top-20 ----------------
__global__ __launch_bounds__(256) void k_sel(const float* __restrict__ pd,
                                             int* __restrict__ idxb) {
  int tid = threadIdx.x;
  int wave = tid >> 6, lane = tid & 63;
  int bn = blockIdx.x * 4 + wave;
  const float* row = pd + (size_t)bn * 1024;
  int mbase = lane * 16;
  f32x4 r0 = *(const f32x4*)(row + mbase);
  f32x4 r1 = *(const f32x4*)(row + mbase + 4);
  f32x4 r2 = *(const f32x4*)(row + mbase + 8);
  f32x4 r3 = *(const f32x4*)(row + mbase + 12);
  float v[16];
  #pragma unroll
  for (int j = 0; j < 4; ++j) { v[j] = r0[j]; v[4 + j] = r1[j]; v[8 + j] = r2[j]; v[12 + j] = r3[j]; }
  int* outp = idxb + (size_t)bn * K_;
  for (int kk = 0; kk < K_; ++kk) {
    float bv = v[0]; int bj = 0;
    #pragma unroll
    for (int j = 1; j < 16; ++j)
      if (v[j] > bv) { bv = v[j]; bj = j; }
    int bi = mbase + bj;
    #pragma unroll
    for (int off = 1; off < 64; off <<= 1) {
      float ov = __shfl_xor(bv, off);
      int   oi = __shfl_xor(bi, off);
      if (ov > bv || (ov == bv && oi < bi)) { bv = ov; bi = oi; }
    }
    if (lane == 0) outp[kk] = bi;
    #pragma unroll
    for (int j = 0; j < 16; ++j)
      if (bi == mbase + j) v[j] = -INFINITY;
  }
}

// ---------------- xt: [B][60][N] fp32 -> [P1][64] bf16 (pad 4 zeros) ----------------
__global__ __launch_bounds__(256) void k_xt(const float* __restrict__ x,
                                            short* __restrict__ xt) {
  int bn = blockIdx.x * 256 + threadIdx.x;
  int b = bn >> 10, n = bn & 1023;
  const float* xb = x + (size_t)b * D_ * N_ + n;
  short* row = xt + (size_t)bn * 64;
  for (int c = 0; c < 60; ++c) row[c] = f2b(xb[(size_t)c * N_]);
  row[60] = 0; row[61] = 0; row[62] = 0; row[63] = 0;
}

// ---------------- wuv: rows 0..63 = W1a (nbr-ctr part), 64..127 = W1b - W1a ----------------
__global__ __launch_bounds__(256) void k_wuv(const float* __restrict__ w1,
                                             const float* __restrict__ b1,
                                             short* __restrict__ wuv,
                                             float* __restrict__ buv) {
  int t = blockIdx.x * 256 + threadIdx.x;  // 8192
  int o = t >> 6, c = t & 63;
  float v = 0.f;
  if (o < 64) { if (c < 60) v = w1[o * 120 + c]; }
  else { int o2 = o - 64; if (c < 60) v = w1[o2 * 120 + 60 + c] - w1[o2 * 120 + c]; }
  wuv[t] = f2b(v);
  if (t < 128) buv[t] = (t < 64) ? 0.f : b1[t - 64];
}

// ---------------- convert w2..w6 fp32 -> bf16 ----------------
__global__ __launch_bounds__(256) void k_wcvt(const float* __restrict__ w2,
                                              const float* __restrict__ w3,
                                              const float* __restrict__ w4,
                                              const float* __restrict__ w5,
                                              const float* __restrict__ w6,
                                              short* __restrict__ wbase) {
  int t = blockIdx.x * 256 + threadIdx.x;
  if (t < 4096) wbase[WO2 + t] = f2b(w2[t]);
  else if (t < 12288) wbase[WO3 + (t - 4096)] = f2b(w3[t - 4096]);
  else if (t < 45056) wbase[WO4 + (t - 12288)] = f2b(w4[t - 12288]);
  else if (t < 176128) wbase[WO5 + (t - 45056)] = f2b(w5[t - 45056]);
  else if (t < 438272) wbase[WO6 + (t - 176128)] = f2b(w6[t - 176128]);
}

// ---------------- pipelined MFMA GEMM: global_load_lds + XOR swizzle ----------------
// Block = 64 co (one chunk) x NR row-panels of 128; K split into 64-wide panels.
// A(16KB)+W(8KB) double-buffered via global_load_lds (linear LDS dest, inverse-
// swizzled per-lane global source; ds_read applies matching XOR -> ~conflict-free).
// One barrier per panel. APPLY = BN+lrelu applied on A-fragment after ds_read.
// Stats accumulate in registers across all panels (one 512B write/wave/block).
// Max-over-k via segmented shfl + atomicMax (monotone BN+lrelu commutes with max).
template <int K, int COUT, int NR, bool APPLY, bool STATS, bool WMAX, bool HSTORE, bool F32OUT>
__global__ __launch_bounds__(256) void k_gemm(const short* __restrict__ in,
                                              const short* __restrict__ wb,
                                              const float* __restrict__ bias,
                                              const float* __restrict__ Ain,
                                              const float* __restrict__ Bin,
                                              float* __restrict__ part,
                                              short* __restrict__ out,
                                              unsigned* __restrict__ umax) {
  constexpr int NKP = K / 64;
  constexpr int NP  = NR * NKP;
  constexpr int ASZ = 128 * 64;   // shorts
  constexpr int WSZ = 64 * 64;
  __shared__ __align__(16) short ldsA[2 * ASZ];
  __shared__ __align__(16) short ldsW[2 * WSZ];

  int tid = threadIdx.x;
  int w = tid >> 6, lane = tid & 63;
  int ln = lane & 15, quad = lane >> 4;
  int xsl = ln & 7;
  // XCD-bijective swizzle; co-chunks of a row-panel adjacent
  int bid = blockIdx.y * gridDim.x + blockIdx.x;
  int tot = gridDim.x * gridDim.y;
  int gid = (bid & 7) * (tot >> 3) + (bid >> 3);
  int bxx = gid % gridDim.x;
  int rpB = gid / gridDim.x;
  int co0 = bxx * 64;

  const int rl = lane >> 3;
  const int c16 = (lane & 7) ^ (rl & 7);   // inverse-swizzled source slot

  auto stage = [&](int p, int b) {
    const int rp_ = rpB * NR + p / NKP;
    const int kp_ = p % NKP;
    const short* sA = in + (size_t)(rp_ * 128) * K + kp_ * 64;
    #pragma unroll
    for (int i = 0; i < 4; ++i) {
      int ch = w * 4 + i;                      // 16 chunks of 8 rows
      gl16(sA + (size_t)(ch * 8 + rl) * K + c16 * 8, ldsA + b * ASZ + ch * 512);
    }
    const short* sW = wb + (size_t)co0 * K + kp_ * 64;
    #pragma unroll
    for (int i = 0; i < 2; ++i) {
      int ch = w * 2 + i;                      // 8 chunks of 8 rows
      gl16(sW + (size_t)(ch * 8 + rl) * K + c16 * 8, ldsW + b * WSZ + ch * 512);
    }
  };

  auto applyv = [&](bf16x8 v, int kc) -> bf16x8 {
    f32x4 a0 = *(const f32x4*)(Ain + kc);
    f32x4 a1 = *(const f32x4*)(Ain + kc + 4);
    f32x4 b0 = *(const f32x4*)(Bin + kc);
    f32x4 b1 = *(const f32x4*)(Bin + kc + 4);
    #pragma unroll
    for (int j = 0; j < 8; ++j) {
      float aj = j < 4 ? a0[j] : a1[j - 4];
      float bj = j < 4 ? b0[j] : b1[j - 4];
      float f = b2f(v[j]) * aj + bj;
      f = f >= 0.f ? f : 0.2f * f;
      v[j] = f2b(f);
    }
    return v;
  };

  f32x4 acc[4][2];
  float sacc[4][4], ssacc[4][4];
  #pragma unroll
  for (int m = 0; m < 4; ++m)
    #pragma unroll
    for (int j = 0; j < 4; ++j) { sacc[m][j] = 0.f; ssacc[m][j] = 0.f; }

  stage(0, 0);
  __syncthreads();

  for (int p = 0; p < NP; ++p) {
    const int b = p & 1;
    if (p + 1 < NP) stage(p + 1, b ^ 1);
    const int rp_ = rpB * NR + p / NKP;
    const int kp_ = p % NKP;
    if (kp_ == 0) {
      #pragma unroll
      for (int m = 0; m < 4; ++m)
        #pragma unroll
        for (int t = 0; t < 2; ++t) acc[m][t] = (f32x4){0.f, 0.f, 0.f, 0.f};
    }
    #pragma unroll
    for (int ks = 0; ks < 2; ++ks) {
      bf16x8 fw[4], fa[2];
      int sl = ((ks * 4 + quad) ^ xsl) * 8;
      #pragma unroll
      for (int m = 0; m < 4; ++m)
        fw[m] = *(const bf16x8*)(ldsW + b * WSZ + (m * 16 + ln) * 64 + sl);
      #pragma unroll
      for (int t = 0; t < 2; ++t) {
        fa[t] = *(const bf16x8*)(ldsA + b * ASZ + (w * 32 + t * 16 + ln) * 64 + sl);
        if (APPLY) fa[t] = applyv(fa[t], kp_ * 64 + ks * 32 + quad * 8);
      }
      #pragma unroll
      for (int m = 0; m < 4; ++m)
        #pragma unroll
        for (int t = 0; t < 2; ++t)
          acc[m][t] = __builtin_amdgcn_mfma_f32_16x16x32_bf16(fw[m], fa[t], acc[m][t], 0, 0, 0);
    }
    if (kp_ == NKP - 1) {
      // bias
      #pragma unroll
      for (int m = 0; m < 4; ++m) {
        f32x4 bs = *(const f32x4*)(bias + co0 + m * 16 + quad * 4);
        #pragma unroll
        for (int t = 0; t < 2; ++t)
          #pragma unroll
          for (int j = 0; j < 4; ++j) acc[m][t][j] += bs[j];
      }
      const int prow = rp_ * 128 + w * 32;
      if (HSTORE) {
        #pragma unroll
        for (int m = 0; m < 4; ++m)
          #pragma unroll
          for (int t = 0; t < 2; ++t) {
            int pp_ = prow + t * 16 + ln;
            if (F32OUT) {
              *(f32x4*)((float*)out + (size_t)pp_ * COUT + co0 + m * 16 + quad * 4) = acc[m][t];
            } else {
              bf16x4 o;
              #pragma unroll
              for (int jr = 0; jr < 4; ++jr) o[jr] = f2b(acc[m][t][jr]);
              *(bf16x4*)(out + (size_t)pp_ * COUT + co0 + m * 16 + quad * 4) = o;
            }
          }
      }
      if (STATS) {
        #pragma unroll
        for (int m = 0; m < 4; ++m)
          #pragma unroll
          for (int j = 0; j < 4; ++j) {
            float v0 = acc[m][0][j], v1 = acc[m][1][j];
            float s = v0 + v1, ss = v0 * v0 + v1 * v1;
            #pragma unroll
            for (int off = 1; off < 16; off <<= 1) {
              s += __shfl_xor(s, off); ss += __shfl_xor(ss, off);
            }
            sacc[m][j] += s; ssacc[m][j] += ss;
          }
      }
      if (WMAX) {
        #pragma unroll
        for (int t = 0; t < 2; ++t) {
          int row = prow + t * 16 + ln;
          int g = row / 20;
          bool lead = (ln == 0) || (row - g * 20 == 0);
          int og1 = __shfl_xor(g, 1), og2 = __shfl_xor(g, 2);
          int og4 = __shfl_xor(g, 4), og8 = __shfl_xor(g, 8);
          #pragma unroll
          for (int m = 0; m < 4; ++m)
            #pragma unroll
            for (int j = 0; j < 4; ++j) {
              float v = acc[m][t][j];
              float ov;
              ov = __shfl_xor(v, 1); if (og1 == g && ov > v) v = ov;
              ov = __shfl_xor(v, 2); if (og2 == g && ov > v) v = ov;
              ov = __shfl_xor(v, 4); if (og4 == g && ov > v) v = ov;
              ov = __shfl_xor(v, 8); if (og8 == g && ov > v) v = ov;
              if (lead) atomicMax(&umax[(size_t)g * COUT + co0 + m * 16 + quad * 4 + j], fenc(v));
            }
        }
      }
    }
    __syncthreads();
  }
  if (STATS && ln == 0) {
    size_t key = ((size_t)bxx * gridDim.y + rpB) * 4 + w;
    float* pp = part + key * 128;
    #pragma unroll
    for (int m = 0; m < 4; ++m)
      #pragma unroll
      for (int j = 0; j < 4; ++j) {
        pp[m * 16 + quad * 4 + j] = sacc[m][j];
        pp[64 + m * 16 + quad * 4 + j] = ssacc[m][j];
      }
  }
}

// ---------------- expand: h1[(n,k),c] = U[nbr,c] + V[n,c]; fused stats + max ----------------
__global__ __launch_bounds__(256) void k_expand(const float* __restrict__ UVf,
                                                const int* __restrict__ idxb,
                                                short* __restrict__ h1,
                                                float* __restrict__ xr1,
                                                float* __restrict__ part) {
  int tid = threadIdx.x;
  int lp = tid >> 4;
  int c0 = (tid & 15) * 4;
  int pt = blockIdx.x * 16 + lp;
  int base = (pt >> 10) << 10;
  f32x4 V = *(const f32x4*)(UVf + (size_t)pt * 128 + 64 + c0);
  f32x4 sum = (f32x4){0.f, 0.f, 0.f, 0.f};
  f32x4 ssq = (f32x4){0.f, 0.f, 0.f, 0.f};
  f32x4 mx = (f32x4){-INFINITY, -INFINITY, -INFINITY, -INFINITY};
  const int* ip = idxb + (size_t)pt * K_;
  size_t hb = (size_t)pt * K_ * 64 + c0;
  for (int k = 0; k < K_; ++k) {
    int nb = base + ip[k];
    f32x4 U = *(const f32x4*)(UVf + (size_t)nb * 128 + c0);
    bf16x4 o;
    #pragma unroll
    for (int j = 0; j < 4; ++j) {
      float h = U[j] + V[j];
      mx[j] = fmaxf(mx[j], U[j]);
      sum[j] += h; ssq[j] += h * h;
      o[j] = f2b(h);
    }
    *(bf16x4*)(h1 + hb + (size_t)k * 64) = o;
  }
  f32x4 xo;
  #pragma unroll
  for (int j = 0; j < 4; ++j) xo[j] = mx[j] + V[j];
  *(f32x4*)(xr1 + (size_t)pt * 64 + c0) = xo;
  __shared__ float ls[2048];
  *(f32x4*)(ls + tid * 4) = sum;
  *(f32x4*)(ls + 1024 + tid * 4) = ssq;
  __syncthreads();
  if (tid < 32) {
    int cl = tid & 15;
    bool issq = tid >= 16;
    const float* src = ls + (issq ? 1024 : 0);
    f32x4 s = (f32x4){0.f, 0.f, 0.f, 0.f};
    #pragma unroll
    for (int g = 0; g < 16; ++g) {
      f32x4 v = *(const f32x4*)(src + (g * 16 + cl) * 4);
      s[0] += v[0]; s[1] += v[1]; s[2] += v[2]; s[3] += v[3];
    }
    *(f32x4*)(part + (size_t)blockIdx.x * 128 + (issq ? 64 : 0) + cl * 4) = s;
  }
}

// ---------------- stage-1 reduction: part[cc][NB][128] -> part2[cc][32][128] ----------------
__global__ __launch_bounds__(256) void k_red(const float* __restrict__ part, int NB,
                                             float* __restrict__ part2) {
  int cc = blockIdx.x, by = blockIdx.y;
  int tid = threadIdx.x;
  int rg = tid >> 5;
  int c4 = (tid & 31) * 4;
  int chunk = NB >> 5;
  const float* p = part + ((size_t)cc * NB + (size_t)by * chunk) * 128;
  f32x4 acc = (f32x4){0.f, 0.f, 0.f, 0.f};
  for (int r = rg; r < chunk; r += 8) {
    f32x4 v = *(const f32x4*)(p + (size_t)r * 128 + c4);
    acc[0] += v[0]; acc[1] += v[1]; acc[2] += v[2]; acc[3] += v[3];
  }
  __shared__ float lds[1024];
  *(f32x4*)(lds + tid * 4) = acc;
  __syncthreads();
  if (tid < 32) {
    f32x4 s = (f32x4){0.f, 0.f, 0.f, 0.f};
    #pragma unroll
    for (int g = 0; g < 8; ++g) {
      f32x4 v = *(const f32x4*)(lds + (g * 32 + tid) * 4);
      s[0] += v[0]; s[1] += v[1]; s[2] += v[2]; s[3] += v[3];
    }
    *(f32x4*)(part2 + ((size_t)cc * 32 + by) * 128 + tid * 4) = s;
  }
}

// ---------------- reduce partials -> A = g*rsqrt(var+eps), B = be - mean*A ----------------
__global__ __launch_bounds__(256) void k_bnab(const float* __restrict__ part, int NB,
                                              const float* __restrict__ g,
                                              const float* __restrict__ be,
                                              float* __restrict__ A,
                                              float* __restrict__ Bp, float inv) {
  __shared__ float red[256];
  int tid = threadIdx.x;
  int j = tid & 127, h = tid >> 7;
  const float* p = part + (size_t)blockIdx.x * NB * 128;
  float s = 0.f;
  for (int bx = h; bx < NB; bx += 2) s += p[(size_t)bx * 128 + j];
  red[tid] = s;
  __syncthreads();
  if (tid < 128) red[tid] = red[tid] + red[tid + 128];
  __syncthreads();
  if (tid < 64) {
    int c = blockIdx.x * 64 + tid;
    float m = red[tid] * inv;
    float v = red[64 + tid] * inv - m * m;
    float a = g[c] * rsqrtf(v + 1e-5f);
    A[c] = a; Bp[c] = be[c] - m * a;
  }
}

// ---------------- xcat: decode raw maxes, apply BN+lrelu, pack [P1][512] bf16 ----------------
__global__ __launch_bounds__(256) void k_xcat(const float* __restrict__ xr1,
                                              const unsigned* __restrict__ xr2,
                                              const unsigned* __restrict__ xr3,
                                              const unsigned* __restrict__ xr4,
                                              const float* __restrict__ A,
                                              const float* __restrict__ Bp,
                                              short* __restrict__ xcat) {
  int t = blockIdx.x * 256 + threadIdx.x;  // P1*128
  int p = t >> 7, cq = t & 127;
  int c0 = cq * 4;
  f32x4 v;
  if (c0 < 64) {
    v = *(const f32x4*)(xr1 + (size_t)p * 64 + c0);
  } else {
    const unsigned* src; int cc;
    if (c0 < 128)      { src = xr2 + (size_t)p * 64;  cc = c0 - 64; }
    else if (c0 < 256) { src = xr3 + (size_t)p * 128; cc = c0 - 128; }
    else               { src = xr4 + (size_t)p * 256; cc = c0 - 256; }
    #pragma unroll
    for (int j = 0; j < 4; ++j) v[j] = fdec(src[cc + j]);
  }
  f32x4 a = *(const f32x4*)(A + c0);
  f32x4 b = *(const f32x4*)(Bp + c0);
  bf16x4 o;
  #pragma unroll
  for (int j = 0; j < 4; ++j) {
    float f = v[j] * a[j] + b[j];
    f = f >= 0.f ? f : 0.2f * f;
    o[j] = f2b(f);
  }
  *(bf16x4*)(xcat + (size_t)p * 512 + c0) = o;
}

// ---------------- final: BN+lrelu bf16 [P1][1024] -> fp32 out ----------------
__global__ __launch_bounds__(256) void k_apply_out(const short* __restrict__ h,
                                                   const float* __restrict__ A,
                                                   const float* __restrict__ Bp,
                                                   float* __restrict__ out) {
  int t = blockIdx.x * 256 + threadIdx.x;
  int c0 = (t & 255) * 4;
  f32x4 a = *(const f32x4*)(A + c0);
  f32x4 b = *(const f32x4*)(Bp + c0);
  bf16x4 v = *(const bf16x4*)(h + (size_t)t * 4);
  f32x4 o;
  #pragma unroll
  for (int r = 0; r < 4; ++r) {
    float f = b2f(v[r]) * a[r] + b[r];
    o[r] = f >= 0.f ? f : 0.2f * f;
  }
  *(f32x4*)(out + (size_t)t * 4) = o;
}

extern "C" void kernel_launch(void* const* d_in, const int* in_sizes, int n_in,
                              void* d_out, int out_size, void* d_ws, size_t ws_size,
                              hipStream_t stream) {
  const float* x   = (const float*)d_in[0];
  const float* w1  = (const float*)d_in[1];
  const float* b1  = (const float*)d_in[2];
  const float* g1  = (const float*)d_in[3];
  const float* be1 = (const float*)d_in[4];
  const float* w2  = (const float*)d_in[5];
  const float* b2  = (const float*)d_in[6];
  const float* g2  = (const float*)d_in[7];
  const float* be2 = (const float*)d_in[8];
  const float* w3  = (const float*)d_in[9];
  const float* b3  = (const float*)d_in[10];
  const float* g3  = (const float*)d_in[11];
  const float* be3 = (const float*)d_in[12];
  const float* w4  = (const float*)d_in[13];
  const float* b4  = (const float*)d_in[14];
  const float* g4  = (const float*)d_in[15];
  const float* be4 = (const float*)d_in[16];
  const float* w5  = (const float*)d_in[17];
  const float* b5  = (const float*)d_in[18];
  const float* g5  = (const float*)d_in[19];
  const float* be5 = (const float*)d_in[20];
  const float* w6  = (const float*)d_in[21];
  const float* b6  = (const float*)d_in[22];
  const float* g6  = (const float*)d_in[23];
  const float* be6 = (const float*)d_in[24];
  float* out = (float*)d_out;
  char* ws = (char*)d_ws;

  int*      idxb = (int*)(ws + OFF_IDX);
  float*    xx   = (float*)(ws + OFF_XX);
  float*    Aall = (float*)(ws + OFF_STATS);
  float*    Ball = Aall + NCH_TOT;
  float*    buv  = Ball + NCH_TOT;
  short*    xt   = (short*)(ws + OFF_XT);
  short*    wbb  = (short*)(ws + OFF_WB);
  short*    xcat = (short*)(ws + OFF_XC);
  short*    h5   = (short*)(ws + OFF_H5);
  short*    h6   = (short*)(ws + OFF_H6);
  float*    UVf  = (float*)(ws + OFF_UV);
  float*    xr1  = (float*)(ws + OFF_XR1);
  unsigned* xr2  = (unsigned*)(ws + OFF_XR2);
  unsigned* xr3  = (unsigned*)(ws + OFF_XR3);
  unsigned* xr4  = (unsigned*)(ws + OFF_XR4);
  short*    h1   = (short*)(ws + OFF_H1);
  short*    h2   = (short*)(ws + OFF_H2);
  short*    h3   = (short*)(ws + OFF_H3);
  float*    pd    = (float*)(ws + OFF_H3);   // aliases h3; consumed before h3 written
  float*    part  = (float*)(ws + OFF_PART);
  float*    part2 = (float*)(ws + OFF_PART2);

  // init ordered-key max buffers (key 0 < key(-inf))
  hipMemsetAsync(ws + OFF_XR2, 0, 2097152ull + 4194304ull + 8388608ull, stream);

  k_xx <<<P1_ / 256, 256, 0, stream>>>(x, xx);
  k_pd <<<dim3(8, 16, 8), 256, 0, stream>>>(x, xx, pd);
  k_sel<<<P1_ / 4, 256, 0, stream>>>(pd, idxb);
  k_xt <<<P1_ / 256, 256, 0, stream>>>(x, xt);
  k_wuv<<<32, 256, 0, stream>>>(w1, b1, wbb + WO1, buv);
  k_wcvt<<<1712, 256, 0, stream>>>(w2, w3, w4, w5, w6, wbb);

  // layer 1 factorized: UV[P1][128] fp32 = [W1a·x | (W1b-W1a)·x + b1]
  k_gemm<64, 128, 1, false, false, false, true, true><<<dim3(2, 64), 256, 0, stream>>>(
      xt, wbb + WO1, buv, nullptr, nullptr, nullptr, (short*)UVf, nullptr);
  // expand: h1 = U[nbr]+V, fused stats partials + raw max -> xr1
  k_expand<<<P1_ / 16, 256, 0, stream>>>(UVf, idxb, h1, xr1, part);
  k_red <<<dim3(1, 32), 256, 0, stream>>>(part, P1_ / 16, part2);
  k_bnab<<<1, 256, 0, stream>>>(part2, 32, g1, be1, Aall + SO1, Ball + SO1, 1.f / P2_);

  // layer 2: act(h1) x w2 -> h2 + stats + raw max -> xr2 ; NR=2
  k_gemm<64, 64, 2, true, true, true, true, false><<<dim3(1, 640), 256, 0, stream>>>(
      h1, wbb + WO2, b2, Aall + SO1, Ball + SO1, part, h2, xr2);
  k_red <<<dim3(1, 32), 256, 0, stream>>>(part, 2560, part2);
  k_bnab<<<1, 256, 0, stream>>>(part2, 32, g2, be2, Aall + SO2, Ball + SO2, 1.f / P2_);

  // layer 3: act(h2) x w3 -> h3 + stats + raw max -> xr3 ; NR=2
  k_gemm<64, 128, 2, true, true, true, true, false><<<dim3(2, 640), 256, 0, stream>>>(
      h2, wbb + WO3, b3, Aall + SO2, Ball + SO2, part, h3, xr3);
  k_red <<<dim3(2, 32), 256, 0, stream>>>(part, 2560, part2);
  k_bnab<<<2, 256, 0, stream>>>(part2, 32, g3, be3, Aall + SO3, Ball + SO3, 1.f / P2_);

  // layer 4: act(h3) x w4 -> stats + raw max only ; NR=4, 8 panels/block
  k_gemm<128, 256, 4, true, true, true, false, false><<<dim3(4, 320), 256, 0, stream>>>(
      h3, wbb + WO4, b4, Aall + SO3, Ball + SO3, part, nullptr, xr4);
  k_red <<<dim3(4, 32), 256, 0, stream>>>(part, 1280, part2);
  k_bnab<<<4, 256, 0, stream>>>(part2, 32, g4, be4, Aall + SO4, Ball + SO4, 1.f / P2_);

  // assemble xcat from raw maxes with BN+lrelu
  k_xcat<<<P1_ * 128 / 256, 256, 0, stream>>>(xr1, xr2, xr3, xr4, Aall, Ball, xcat);

  // layer 5: xcat x w5 -> h5 + stats ; 8 k-panels/block
  k_gemm<512, 256, 1, false, true, false, true, false><<<dim3(4, 64), 256, 0, stream>>>(
      xcat, wbb + WO5, b5, nullptr, nullptr, part, h5, nullptr);
  k_bnab<<<4, 256, 0, stream>>>(part, 256, g5, be5, Aall + SO5, Ball + SO5, 1.f / P1_);

  // layer 6: act(h5) x w6 -> h6 + stats ; 4 k-panels/block
  k_gemm<256, 1024, 1, true, true, false, true, false><<<dim3(16, 64), 256, 0, stream>>>(
      h5, wbb + WO6, b6, Aall + SO5, Ball + SO5, part, h6, nullptr);
  k_bnab<<<16, 256, 0, stream>>>(part, 256, g6, be6, Aall + SO6, Ball + SO6, 1.f / P1_);
  k_apply_out<<<P1_ * 256 / 256, 256, 0, stream>>>(h6, Aall + SO6, Ball + SO6, out);

  (void)in_sizes; (void)n_in; (void)out_size; (void)ws_size;
}

// Round 6
// 522.788 us; speedup vs baseline: 1.1231x; 1.1151x over previous
//
#include <hip/hip_runtime.h>
#include <hip/hip_bf16.h>
#include <math.h>

#define B_ 8
#define D_ 60
#define N_ 1024
#define K_ 20
#define P1_ 8192      // B*N
#define P2_ 163840    // B*N*K

typedef __attribute__((ext_vector_type(8))) short bf16x8;
typedef __attribute__((ext_vector_type(4))) short bf16x4;
typedef __attribute__((ext_vector_type(4))) float f32x4;
typedef __attribute__((ext_vector_type(4))) unsigned u32x4;

__device__ inline float b2f(short s) { return __uint_as_float(((unsigned)(unsigned short)s) << 16); }
__device__ inline short f2b(float f) { __hip_bfloat16 h = __float2bfloat16(f); return *(short*)&h; }
// order-preserving float<->uint key
__device__ inline unsigned fenc(float f) { unsigned b = __float_as_uint(f); return (b & 0x80000000u) ? ~b : (b | 0x80000000u); }
__device__ inline float fdec(unsigned k) { return __uint_as_float((k & 0x80000000u) ? (k ^ 0x80000000u) : ~k); }

// async global->LDS, 16B per lane; lds dest = wave-uniform base + lane*16
__device__ __forceinline__ void gl16(const short* g, short* l) {
  __builtin_amdgcn_global_load_lds(
      (const __attribute__((address_space(1))) unsigned int*)g,
      (__attribute__((address_space(3))) unsigned int*)l, 16, 0, 0);
}

// ---- workspace layout (bytes), all 256-aligned ----
#define OFF_IDX   0ull          // int[P1][20] = 655360
#define OFF_XX    655360ull     // float[P1]
#define OFF_STATS 688128ull     // A[1792], B[1792], buv[128]
#define OFF_XT    720896ull     // bf16[P1][64] = 1MB
#define OFF_WB    1769472ull    // bf16 weights (wuv at WO1)
#define OFF_XC    2662400ull    // bf16[P1][512] = 8MB
#define OFF_H5    11051008ull   // bf16[P1][256] = 4MB
#define OFF_H6    15245312ull   // bf16[P1][1024] = 16MB
#define OFF_UV    32022528ull   // fp32[P1][128] = 4MB  (U | V)
#define OFF_XR1   36216832ull   // fp32[P1][64] = 2MB   raw max layer1
#define OFF_XR2   38313984ull   // uint[P1][64] = 2MB   key-coded max layer2
#define OFF_XR3   40411136ull   // uint[P1][128] = 4MB
#define OFF_XR4   44605440ull   // uint[P1][256] = 8MB
#define OFF_H1    52994048ull   // bf16[P2][64] = 20MB
#define OFF_H2    73965568ull   // bf16[P2][64] = 20MB
#define OFF_H3    94937088ull   // bf16[P2][128] = 40MB ; pd (33.5MB fp32) aliases here
#define OFF_PART  136880128ull  // float partial stats (max 4cc*1024*128*4 = 2MB)
#define OFF_PART2 149463040ull  // float stage-2 partials, 64KB
// end ~149.6 MiB

#define WO1 0
#define WO2 8192
#define WO3 12288
#define WO4 20480
#define WO5 53248
#define WO6 184320

#define SO1 0
#define SO2 64
#define SO3 128
#define SO4 256
#define SO5 512
#define SO6 768
#define NCH_TOT 1792

// ---------------- xx[bn] = sum_d x^2 ----------------
__global__ __launch_bounds__(256) void k_xx(const float* __restrict__ x,
                                            float* __restrict__ xx) {
  int bn = blockIdx.x * 256 + threadIdx.x;
  int b = bn >> 10, n = bn & 1023;
  const float* xb = x + (size_t)b * D_ * N_ + n;
  float s = 0.f;
  for (int d = 0; d < D_; ++d) { float v = xb[(size_t)d * N_]; s += v * v; }
  xx[bn] = s;
}

// ---------------- pd[b][n][m] = 2*dot - xx_n - xx_m ; tiled fp32 ----------------
__global__ __launch_bounds__(256) void k_pd(const float* __restrict__ x,
                                            const float* __restrict__ xx,
                                            float* __restrict__ pd) {
  __shared__ float lnn[D_][64];
  __shared__ float lmm[D_][128];
  int tid = threadIdx.x;
  int m0 = blockIdx.x * 128, n0 = blockIdx.y * 64, b = blockIdx.z;
  const float* xb = x + (size_t)b * D_ * N_;
  #pragma unroll
  for (int i = 0; i < 15; ++i) {
    int idx = tid + i * 256;
    int d = idx >> 6, col = idx & 63;
    lnn[d][col] = xb[(size_t)d * N_ + n0 + col];
  }
  #pragma unroll
  for (int i = 0; i < 30; ++i) {
    int idx = tid + i * 256;
    int d = idx >> 7, col = idx & 127;
    lmm[d][col] = xb[(size_t)d * N_ + m0 + col];
  }
  __syncthreads();
  int tn = tid >> 5, tm = tid & 31;
  float acc[8][4];
  #pragma unroll
  for (int i = 0; i < 8; ++i)
    #pragma unroll
    for (int j = 0; j < 4; ++j) acc[i][j] = 0.f;
  for (int d = 0; d < D_; ++d) {
    f32x4 mv  = *(const f32x4*)&lmm[d][tm * 4];
    f32x4 nva = *(const f32x4*)&lnn[d][tn * 8];
    f32x4 nvb = *(const f32x4*)&lnn[d][tn * 8 + 4];
    #pragma unroll
    for (int i = 0; i < 4; ++i)
      #pragma unroll
      for (int j = 0; j < 4; ++j) {
        acc[i][j]     = fmaf(nva[i], mv[j], acc[i][j]);
        acc[4 + i][j] = fmaf(nvb[i], mv[j], acc[4 + i][j]);
      }
  }
  const float* xxb = xx + b * 1024;
  f32x4 xxm = *(const f32x4*)(xxb + m0 + tm * 4);
  #pragma unroll
  for (int i = 0; i < 8; ++i) {
    int n = n0 + tn * 8 + i;
    float xxn = xxb[n];
    f32x4 o;
    #pragma unroll
    for (int j = 0; j < 4; ++j) o[j] = 2.f * acc[i][j] - xxn - xxm[j];
    *(f32x4*)(pd + ((size_t)(b * 1024 + n) * 1024) + m0 + tm * 4) = o;
  }
}

// ---------------- selection: one wave per point, top-20 ----------------
__global__ __launch_bounds__(256) void k_sel(const float* __restrict__ pd,
                                             int* __restrict__ idxb) {
  int tid = threadIdx.x;
  int wave = tid >> 6, lane = tid & 63;
  int bn = blockIdx.x * 4 + wave;
  const float* row = pd + (size_t)bn * 1024;
  int mbase = lane * 16;
  f32x4 r0 = *(const f32x4*)(row + mbase);
  f32x4 r1 = *(const f32x4*)(row + mbase + 4);
  f32x4 r2 = *(const f32x4*)(row + mbase + 8);
  f32x4 r3 = *(const f32x4*)(row + mbase + 12);
  float v[16];
  #pragma unroll
  for (int j = 0; j < 4; ++j) { v[j] = r0[j]; v[4 + j] = r1[j]; v[8 + j] = r2[j]; v[12 + j] = r3[j]; }
  int* outp = idxb + (size_t)bn * K_;
  for (int kk = 0; kk < K_; ++kk) {
    float bv = v[0]; int bj = 0;
    #pragma unroll
    for (int j = 1; j < 16; ++j)
      if (v[j] > bv) { bv = v[j]; bj = j; }
    int bi = mbase + bj;
    #pragma unroll
    for (int off = 1; off < 64; off <<= 1) {
      float ov = __shfl_xor(bv, off);
      int   oi = __shfl_xor(bi, off);
      if (ov > bv || (ov == bv && oi < bi)) { bv = ov; bi = oi; }
    }
    if (lane == 0) outp[kk] = bi;
    #pragma unroll
    for (int j = 0; j < 16; ++j)
      if (bi == mbase + j) v[j] = -INFINITY;
  }
}

// ---------------- xt: [B][60][N] fp32 -> [P1][64] bf16 (pad 4 zeros) ----------------
__global__ __launch_bounds__(256) void k_xt(const float* __restrict__ x,
                                            short* __restrict__ xt) {
  int bn = blockIdx.x * 256 + threadIdx.x;
  int b = bn >> 10, n = bn & 1023;
  const float* xb = x + (size_t)b * D_ * N_ + n;
  short* row = xt + (size_t)bn * 64;
  for (int c = 0; c < 60; ++c) row[c] = f2b(xb[(size_t)c * N_]);
  row[60] = 0; row[61] = 0; row[62] = 0; row[63] = 0;
}

// ---------------- wuv: rows 0..63 = W1a, 64..127 = W1b - W1a ----------------
__global__ __launch_bounds__(256) void k_wuv(const float* __restrict__ w1,
                                             const float* __restrict__ b1,
                                             short* __restrict__ wuv,
                                             float* __restrict__ buv) {
  int t = blockIdx.x * 256 + threadIdx.x;  // 8192
  int o = t >> 6, c = t & 63;
  float v = 0.f;
  if (o < 64) { if (c < 60) v = w1[o * 120 + c]; }
  else { int o2 = o - 64; if (c < 60) v = w1[o2 * 120 + 60 + c] - w1[o2 * 120 + c]; }
  wuv[t] = f2b(v);
  if (t < 128) buv[t] = (t < 64) ? 0.f : b1[t - 64];
}

// ---------------- convert w2..w6 fp32 -> bf16 ----------------
__global__ __launch_bounds__(256) void k_wcvt(const float* __restrict__ w2,
                                              const float* __restrict__ w3,
                                              const float* __restrict__ w4,
                                              const float* __restrict__ w5,
                                              const float* __restrict__ w6,
                                              short* __restrict__ wbase) {
  int t = blockIdx.x * 256 + threadIdx.x;
  if (t < 4096) wbase[WO2 + t] = f2b(w2[t]);
  else if (t < 12288) wbase[WO3 + (t - 4096)] = f2b(w3[t - 4096]);
  else if (t < 45056) wbase[WO4 + (t - 12288)] = f2b(w4[t - 12288]);
  else if (t < 176128) wbase[WO5 + (t - 45056)] = f2b(w5[t - 45056]);
  else if (t < 438272) wbase[WO6 + (t - 176128)] = f2b(w6[t - 176128]);
}

// ---------------- MFMA GEMM v2: W-in-regs, A via gl16+swizzle, aligned blocks ----
// Block covers NR*128 rows x NCO*64 cols. A panels [128][64] double-buffered via
// global_load_lds (linear dest, inverse-swizzled source; matching XOR on ds_read).
// W fragments register-resident (per-lane 16B global loads, L2-hot). 1 barrier/panel.
// Stats in registers across all panels, one shfl-reduce + store per wave per block.
// WMAX: NR=5 -> 640 rows = exactly 32 neighbor-groups per block -> per-finalize LDS
// reduce + PLAIN stores (no atomics, no init); straddle groups carried in LDS.
template <int K, int COUT, int NCO, int NR, bool APPLY, bool STATS, bool WMAX, bool HSTORE, bool F32OUT>
__global__ __launch_bounds__(256) void k_gemm(const short* __restrict__ in,
                                              const short* __restrict__ wb,
                                              const float* __restrict__ bias,
                                              const float* __restrict__ Ain,
                                              const float* __restrict__ Bin,
                                              float* __restrict__ part,
                                              short* __restrict__ out,
                                              unsigned* __restrict__ umax) {
  constexpr int NKP = K / 64;
  constexpr int NP  = NR * NKP;
  constexpr int ASZ = 128 * 64;                  // shorts per A buffer
  constexpr int MXSZ = WMAX ? 128 * 68 : 4;
  __shared__ __align__(16) short ldsA[2 * ASZ];
  __shared__ __align__(16) float mx[MXSZ];
  __shared__ float gcarry[2][NCO][64];

  int tid = threadIdx.x;
  int w = tid >> 6, lane = tid & 63;
  int ln = lane & 15, quad = lane >> 4;
  int xsl = ln & 7;
  // XCD-bijective swizzle (total blocks always a multiple of 8)
  int bid = blockIdx.y * gridDim.x + blockIdx.x;
  int tot = gridDim.x * gridDim.y;
  int gid = (bid & 7) * (tot >> 3) + (bid >> 3);
  int bxx = gid % gridDim.x;
  int rpB = gid / gridDim.x;
  const int co00 = bxx * NCO * 64;

  const int rl = lane >> 3;
  const int c16 = (lane & 7) ^ (rl & 7);         // inverse-swizzled source slot

  auto stage = [&](int i2, int b) {
    const short* sA = in + (size_t)((rpB * NR + i2 / NKP) * 128) * K + (i2 % NKP) * 64;
    #pragma unroll
    for (int c = 0; c < 4; ++c) {
      int ch = w * 4 + c;                        // 16 chunks of 8 rows
      gl16(sA + (size_t)(ch * 8 + rl) * K + c16 * 8, ldsA + b * ASZ + ch * 512);
    }
  };

  bf16x8 wf[NCO][4][2];
  auto loadW = [&](int kp_) {
    #pragma unroll
    for (int co = 0; co < NCO; ++co)
      #pragma unroll
      for (int m = 0; m < 4; ++m)
        #pragma unroll
        for (int ks = 0; ks < 2; ++ks)
          wf[co][m][ks] = *(const bf16x8*)(wb + (size_t)(co00 + co * 64 + m * 16 + ln) * K +
                                           kp_ * 64 + ks * 32 + quad * 8);
  };

  auto applyv = [&](bf16x8 v, int kc) -> bf16x8 {
    f32x4 a0 = *(const f32x4*)(Ain + kc);
    f32x4 a1 = *(const f32x4*)(Ain + kc + 4);
    f32x4 b0 = *(const f32x4*)(Bin + kc);
    f32x4 b1 = *(const f32x4*)(Bin + kc + 4);
    #pragma unroll
    for (int j = 0; j < 8; ++j) {
      float aj = j < 4 ? a0[j] : a1[j - 4];
      float bj = j < 4 ? b0[j] : b1[j - 4];
      float f = b2f(v[j]) * aj + bj;
      f = f >= 0.f ? f : 0.2f * f;
      v[j] = f2b(f);
    }
    return v;
  };

  f32x4 acc[NCO][4][2];
  f32x4 ssum[NCO][4], ssqv[NCO][4];
  #pragma unroll
  for (int co = 0; co < NCO; ++co)
    #pragma unroll
    for (int m = 0; m < 4; ++m) {
      ssum[co][m] = (f32x4){0.f, 0.f, 0.f, 0.f};
      ssqv[co][m] = (f32x4){0.f, 0.f, 0.f, 0.f};
    }

  stage(0, 0);
  __syncthreads();

  int b = 0;
  for (int i = 0; i < NP; ++i) {
    if (i + 1 < NP) stage(i + 1, b ^ 1);         // prefetch overlaps compute below
    const int kp_ = i % NKP;
    loadW(kp_);
    if (kp_ == 0) {
      #pragma unroll
      for (int co = 0; co < NCO; ++co)
        #pragma unroll
        for (int m = 0; m < 4; ++m)
          #pragma unroll
          for (int t = 0; t < 2; ++t) acc[co][m][t] = (f32x4){0.f, 0.f, 0.f, 0.f};
    }
    #pragma unroll
    for (int ks = 0; ks < 2; ++ks) {
      bf16x8 fa[2];
      int sl = ((ks * 4 + quad) ^ xsl) * 8;
      #pragma unroll
      for (int t = 0; t < 2; ++t) {
        fa[t] = *(const bf16x8*)(ldsA + b * ASZ + (w * 32 + t * 16 + ln) * 64 + sl);
        if (APPLY) fa[t] = applyv(fa[t], kp_ * 64 + ks * 32 + quad * 8);
      }
      #pragma unroll
      for (int co = 0; co < NCO; ++co)
        #pragma unroll
        for (int m = 0; m < 4; ++m)
          #pragma unroll
          for (int t = 0; t < 2; ++t)
            acc[co][m][t] = __builtin_amdgcn_mfma_f32_16x16x32_bf16(wf[co][m][ks], fa[t], acc[co][m][t], 0, 0, 0);
    }
    if (kp_ == NKP - 1) {
      const int r_ = i / NKP;
      const int prow = (rpB * NR + r_) * 128 + w * 32;
      #pragma unroll
      for (int co = 0; co < NCO; ++co) {
        const int co0 = co00 + co * 64;
        #pragma unroll
        for (int m = 0; m < 4; ++m) {
          f32x4 bs = *(const f32x4*)(bias + co0 + m * 16 + quad * 4);
          #pragma unroll
          for (int t = 0; t < 2; ++t)
            #pragma unroll
            for (int j = 0; j < 4; ++j) acc[co][m][t][j] += bs[j];
        }
        if (HSTORE) {
          #pragma unroll
          for (int m = 0; m < 4; ++m)
            #pragma unroll
            for (int t = 0; t < 2; ++t) {
              int p = prow + t * 16 + ln;
              if (F32OUT) {
                *(f32x4*)((float*)out + (size_t)p * COUT + co0 + m * 16 + quad * 4) = acc[co][m][t];
              } else {
                bf16x4 o;
                #pragma unroll
                for (int jr = 0; jr < 4; ++jr) o[jr] = f2b(acc[co][m][t][jr]);
                *(bf16x4*)(out + (size_t)p * COUT + co0 + m * 16 + quad * 4) = o;
              }
            }
        }
        if (STATS) {
          #pragma unroll
          for (int m = 0; m < 4; ++m) {
            ssum[co][m] += acc[co][m][0] + acc[co][m][1];
            ssqv[co][m] += acc[co][m][0] * acc[co][m][0] + acc[co][m][1] * acc[co][m][1];
          }
        }
      }
      if (WMAX) {
        const int rb = r_ * 128;                  // local row base in block
        const int lg0 = rb / 20, lg1 = (rb + 127) / 20;
        const int cnt = lg1 - lg0 + 1;
        #pragma unroll
        for (int co = 0; co < NCO; ++co) {
          __syncthreads();                        // mx free (prev reads done)
          #pragma unroll
          for (int m = 0; m < 4; ++m)
            #pragma unroll
            for (int t = 0; t < 2; ++t)
              *(f32x4*)(mx + (size_t)(w * 32 + t * 16 + ln) * 68 + m * 16 + quad * 4) = acc[co][m][t];
          __syncthreads();
          if (tid < cnt * 16) {
            int lg = lg0 + (tid >> 4);
            int c0 = (tid & 15) * 4;
            int grs = lg * 20, gre = grs + 20;
            int rs = grs < rb ? rb : grs;
            int re = gre > rb + 128 ? rb + 128 : gre;
            f32x4 mv = (f32x4){-INFINITY, -INFINITY, -INFINITY, -INFINITY};
            for (int r = rs; r < re; ++r) {
              f32x4 v = *(const f32x4*)(mx + (size_t)(r - rb) * 68 + c0);
              #pragma unroll
              for (int j = 0; j < 4; ++j) mv[j] = fmaxf(mv[j], v[j]);
            }
            if (grs < rb) {                       // merge carry from previous finalize
              f32x4 cv = *(const f32x4*)(&gcarry[(r_ & 1) ^ 1][co][c0]);
              #pragma unroll
              for (int j = 0; j < 4; ++j) mv[j] = fmaxf(mv[j], cv[j]);
            }
            if (gre <= rb + 128) {                // group complete: plain store
              u32x4 o;
              #pragma unroll
              for (int j = 0; j < 4; ++j) o[j] = fenc(mv[j]);
              *(u32x4*)(umax + (size_t)(rpB * 32 + lg) * COUT + co00 + co * 64 + c0) = o;
            } else {                              // carry partial to next finalize
              *(f32x4*)(&gcarry[r_ & 1][co][c0]) = mv;
            }
          }
        }
      }
    }
    __syncthreads();                              // buf b free; buf b^1 landed
    b ^= 1;
  }
  if (STATS) {
    #pragma unroll
    for (int co = 0; co < NCO; ++co) {
      float* pp = part + ((size_t)(bxx * NCO + co) * (gridDim.y * 4) + (size_t)rpB * 4 + w) * 128;
      #pragma unroll
      for (int m = 0; m < 4; ++m)
        #pragma unroll
        for (int j = 0; j < 4; ++j) {
          float s = ssum[co][m][j], q = ssqv[co][m][j];
          #pragma unroll
          for (int off = 1; off < 16; off <<= 1) {
            s += __shfl_xor(s, off); q += __shfl_xor(q, off);
          }
          if (ln == 0) {
            pp[m * 16 + quad * 4 + j] = s;
            pp[64 + m * 16 + quad * 4 + j] = q;
          }
        }
    }
  }
}

// ---------------- expand: h1[(n,k),c] = U[nbr,c] + V[n,c]; fused stats + max ----------------
__global__ __launch_bounds__(256) void k_expand(const float* __restrict__ UVf,
                                                const int* __restrict__ idxb,
                                                short* __restrict__ h1,
                                                float* __restrict__ xr1,
                                                float* __restrict__ part) {
  int tid = threadIdx.x;
  int lp = tid >> 4;
  int c0 = (tid & 15) * 4;
  int pt = blockIdx.x * 16 + lp;
  int base = (pt >> 10) << 10;
  f32x4 V = *(const f32x4*)(UVf + (size_t)pt * 128 + 64 + c0);
  f32x4 sum = (f32x4){0.f, 0.f, 0.f, 0.f};
  f32x4 ssq = (f32x4){0.f, 0.f, 0.f, 0.f};
  f32x4 mx = (f32x4){-INFINITY, -INFINITY, -INFINITY, -INFINITY};
  const int* ip = idxb + (size_t)pt * K_;
  size_t hb = (size_t)pt * K_ * 64 + c0;
  for (int k = 0; k < K_; ++k) {
    int nb = base + ip[k];
    f32x4 U = *(const f32x4*)(UVf + (size_t)nb * 128 + c0);
    bf16x4 o;
    #pragma unroll
    for (int j = 0; j < 4; ++j) {
      float h = U[j] + V[j];
      mx[j] = fmaxf(mx[j], U[j]);
      sum[j] += h; ssq[j] += h * h;
      o[j] = f2b(h);
    }
    *(bf16x4*)(h1 + hb + (size_t)k * 64) = o;
  }
  f32x4 xo;
  #pragma unroll
  for (int j = 0; j < 4; ++j) xo[j] = mx[j] + V[j];
  *(f32x4*)(xr1 + (size_t)pt * 64 + c0) = xo;
  __shared__ float ls[2048];
  *(f32x4*)(ls + tid * 4) = sum;
  *(f32x4*)(ls + 1024 + tid * 4) = ssq;
  __syncthreads();
  if (tid < 32) {
    int cl = tid & 15;
    bool issq = tid >= 16;
    const float* src = ls + (issq ? 1024 : 0);
    f32x4 s = (f32x4){0.f, 0.f, 0.f, 0.f};
    #pragma unroll
    for (int g = 0; g < 16; ++g) {
      f32x4 v = *(const f32x4*)(src + (g * 16 + cl) * 4);
      s[0] += v[0]; s[1] += v[1]; s[2] += v[2]; s[3] += v[3];
    }
    *(f32x4*)(part + (size_t)blockIdx.x * 128 + (issq ? 64 : 0) + cl * 4) = s;
  }
}

// ---------------- stage-1 reduction: part[cc][NB][128] -> part2[cc][32][128] ----------------
__global__ __launch_bounds__(256) void k_red(const float* __restrict__ part, int NB,
                                             float* __restrict__ part2) {
  int cc = blockIdx.x, by = blockIdx.y;
  int tid = threadIdx.x;
  int rg = tid >> 5;
  int c4 = (tid & 31) * 4;
  int chunk = NB >> 5;
  const float* p = part + ((size_t)cc * NB + (size_t)by * chunk) * 128;
  f32x4 acc = (f32x4){0.f, 0.f, 0.f, 0.f};
  for (int r = rg; r < chunk; r += 8) {
    f32x4 v = *(const f32x4*)(p + (size_t)r * 128 + c4);
    acc[0] += v[0]; acc[1] += v[1]; acc[2] += v[2]; acc[3] += v[3];
  }
  __shared__ float lds[1024];
  *(f32x4*)(lds + tid * 4) = acc;
  __syncthreads();
  if (tid < 32) {
    f32x4 s = (f32x4){0.f, 0.f, 0.f, 0.f};
    #pragma unroll
    for (int g = 0; g < 8; ++g) {
      f32x4 v = *(const f32x4*)(lds + (g * 32 + tid) * 4);
      s[0] += v[0]; s[1] += v[1]; s[2] += v[2]; s[3] += v[3];
    }
    *(f32x4*)(part2 + ((size_t)cc * 32 + by) * 128 + tid * 4) = s;
  }
}

// ---------------- reduce partials -> A = g*rsqrt(var+eps), B = be - mean*A ----------------
__global__ __launch_bounds__(256) void k_bnab(const float* __restrict__ part, int NB,
                                              const float* __restrict__ g,
                                              const float* __restrict__ be,
                                              float* __restrict__ A,
                                              float* __restrict__ Bp, float inv) {
  __shared__ float red[256];
  int tid = threadIdx.x;
  int j = tid & 127, h = tid >> 7;
  const float* p = part + (size_t)blockIdx.x * NB * 128;
  float s = 0.f;
  for (int bx = h; bx < NB; bx += 2) s += p[(size_t)bx * 128 + j];
  red[tid] = s;
  __syncthreads();
  if (tid < 128) red[tid] = red[tid] + red[tid + 128];
  __syncthreads();
  if (tid < 64) {
    int c = blockIdx.x * 64 + tid;
    float m = red[tid] * inv;
    float v = red[64 + tid] * inv - m * m;
    float a = g[c] * rsqrtf(v + 1e-5f);
    A[c] = a; Bp[c] = be[c] - m * a;
  }
}

// ---------------- xcat: decode raw maxes, apply BN+lrelu, pack [P1][512] bf16 ----------------
__global__ __launch_bounds__(256) void k_xcat(const float* __restrict__ xr1,
                                              const unsigned* __restrict__ xr2,
                                              const unsigned* __restrict__ xr3,
                                              const unsigned* __restrict__ xr4,
                                              const float* __restrict__ A,
                                              const float* __restrict__ Bp,
                                              short* __restrict__ xcat) {
  int t = blockIdx.x * 256 + threadIdx.x;  // P1*128
  int p = t >> 7, cq = t & 127;
  int c0 = cq * 4;
  f32x4 v;
  if (c0 < 64) {
    v = *(const f32x4*)(xr1 + (size_t)p * 64 + c0);
  } else {
    const unsigned* src; int cc;
    if (c0 < 128)      { src = xr2 + (size_t)p * 64;  cc = c0 - 64; }
    else if (c0 < 256) { src = xr3 + (size_t)p * 128; cc = c0 - 128; }
    else               { src = xr4 + (size_t)p * 256; cc = c0 - 256; }
    #pragma unroll
    for (int j = 0; j < 4; ++j) v[j] = fdec(src[cc + j]);
  }
  f32x4 a = *(const f32x4*)(A + c0);
  f32x4 b = *(const f32x4*)(Bp + c0);
  bf16x4 o;
  #pragma unroll
  for (int j = 0; j < 4; ++j) {
    float f = v[j] * a[j] + b[j];
    f = f >= 0.f ? f : 0.2f * f;
    o[j] = f2b(f);
  }
  *(bf16x4*)(xcat + (size_t)p * 512 + c0) = o;
}

// ---------------- final: BN+lrelu bf16 [P1][1024] -> fp32 out ----------------
__global__ __launch_bounds__(256) void k_apply_out(const short* __restrict__ h,
                                                   const float* __restrict__ A,
                                                   const float* __restrict__ Bp,
                                                   float* __restrict__ out) {
  int t = blockIdx.x * 256 + threadIdx.x;
  int c0 = (t & 255) * 4;
  f32x4 a = *(const f32x4*)(A + c0);
  f32x4 b = *(const f32x4*)(Bp + c0);
  bf16x4 v = *(const bf16x4*)(h + (size_t)t * 4);
  f32x4 o;
  #pragma unroll
  for (int r = 0; r < 4; ++r) {
    float f = b2f(v[r]) * a[r] + b[r];
    o[r] = f >= 0.f ? f : 0.2f * f;
  }
  *(f32x4*)(out + (size_t)t * 4) = o;
}

extern "C" void kernel_launch(void* const* d_in, const int* in_sizes, int n_in,
                              void* d_out, int out_size, void* d_ws, size_t ws_size,
                              hipStream_t stream) {
  const float* x   = (const float*)d_in[0];
  const float* w1  = (const float*)d_in[1];
  const float* b1  = (const float*)d_in[2];
  const float* g1  = (const float*)d_in[3];
  const float* be1 = (const float*)d_in[4];
  const float* w2  = (const float*)d_in[5];
  const float* b2  = (const float*)d_in[6];
  const float* g2  = (const float*)d_in[7];
  const float* be2 = (const float*)d_in[8];
  const float* w3  = (const float*)d_in[9];
  const float* b3  = (const float*)d_in[10];
  const float* g3  = (const float*)d_in[11];
  const float* be3 = (const float*)d_in[12];
  const float* w4  = (const float*)d_in[13];
  const float* b4  = (const float*)d_in[14];
  const float* g4  = (const float*)d_in[15];
  const float* be4 = (const float*)d_in[16];
  const float* w5  = (const float*)d_in[17];
  const float* b5  = (const float*)d_in[18];
  const float* g5  = (const float*)d_in[19];
  const float* be5 = (const float*)d_in[20];
  const float* w6  = (const float*)d_in[21];
  const float* b6  = (const float*)d_in[22];
  const float* g6  = (const float*)d_in[23];
  const float* be6 = (const float*)d_in[24];
  float* out = (float*)d_out;
  char* ws = (char*)d_ws;

  int*      idxb = (int*)(ws + OFF_IDX);
  float*    xx   = (float*)(ws + OFF_XX);
  float*    Aall = (float*)(ws + OFF_STATS);
  float*    Ball = Aall + NCH_TOT;
  float*    buv  = Ball + NCH_TOT;
  short*    xt   = (short*)(ws + OFF_XT);
  short*    wbb  = (short*)(ws + OFF_WB);
  short*    xcat = (short*)(ws + OFF_XC);
  short*    h5   = (short*)(ws + OFF_H5);
  short*    h6   = (short*)(ws + OFF_H6);
  float*    UVf  = (float*)(ws + OFF_UV);
  float*    xr1  = (float*)(ws + OFF_XR1);
  unsigned* xr2  = (unsigned*)(ws + OFF_XR2);
  unsigned* xr3  = (unsigned*)(ws + OFF_XR3);
  unsigned* xr4  = (unsigned*)(ws + OFF_XR4);
  short*    h1   = (short*)(ws + OFF_H1);
  short*    h2   = (short*)(ws + OFF_H2);
  short*    h3   = (short*)(ws + OFF_H3);
  float*    pd    = (float*)(ws + OFF_H3);   // aliases h3; consumed before h3 written
  float*    part  = (float*)(ws + OFF_PART);
  float*    part2 = (float*)(ws + OFF_PART2);

  k_xx <<<P1_ / 256, 256, 0, stream>>>(x, xx);
  k_pd <<<dim3(8, 16, 8), 256, 0, stream>>>(x, xx, pd);
  k_sel<<<P1_ / 4, 256, 0, stream>>>(pd, idxb);
  k_xt <<<P1_ / 256, 256, 0, stream>>>(x, xt);
  k_wuv<<<32, 256, 0, stream>>>(w1, b1, wbb + WO1, buv);
  k_wcvt<<<1712, 256, 0, stream>>>(w2, w3, w4, w5, w6, wbb);

  // layer 1 factorized: UV[P1][128] fp32 = [W1a·x | (W1b-W1a)·x + b1]
  k_gemm<64, 128, 2, 1, false, false, false, true, true><<<dim3(1, 64), 256, 0, stream>>>(
      xt, wbb + WO1, buv, nullptr, nullptr, nullptr, (short*)UVf, nullptr);
  // expand: h1 = U[nbr]+V, fused stats partials + raw max -> xr1
  k_expand<<<P1_ / 16, 256, 0, stream>>>(UVf, idxb, h1, xr1, part);
  k_red <<<dim3(1, 32), 256, 0, stream>>>(part, P1_ / 16, part2);
  k_bnab<<<1, 256, 0, stream>>>(part2, 32, g1, be1, Aall + SO1, Ball + SO1, 1.f / P2_);

  // layer 2: act(h1) x w2 -> h2 + stats + raw max -> xr2 ; 640-row blocks
  k_gemm<64, 64, 1, 5, true, true, true, true, false><<<dim3(1, 256), 256, 0, stream>>>(
      h1, wbb + WO2, b2, Aall + SO1, Ball + SO1, part, h2, xr2);
  k_red <<<dim3(1, 32), 256, 0, stream>>>(part, 1024, part2);
  k_bnab<<<1, 256, 0, stream>>>(part2, 32, g2, be2, Aall + SO2, Ball + SO2, 1.f / P2_);

  // layer 3: act(h2) x w3 -> h3 + stats + raw max -> xr3
  k_gemm<64, 128, 2, 5, true, true, true, true, false><<<dim3(1, 256), 256, 0, stream>>>(
      h2, wbb + WO3, b3, Aall + SO2, Ball + SO2, part, h3, xr3);
  k_red <<<dim3(2, 32), 256, 0, stream>>>(part, 1024, part2);
  k_bnab<<<2, 256, 0, stream>>>(part2, 32, g3, be3, Aall + SO3, Ball + SO3, 1.f / P2_);

  // layer 4: act(h3) x w4 -> stats + raw max only (no h4)
  k_gemm<128, 256, 2, 5, true, true, true, false, false><<<dim3(2, 256), 256, 0, stream>>>(
      h3, wbb + WO4, b4, Aall + SO3, Ball + SO3, part, nullptr, xr4);
  k_red <<<dim3(4, 32), 256, 0, stream>>>(part, 1024, part2);
  k_bnab<<<4, 256, 0, stream>>>(part2, 32, g4, be4, Aall + SO4, Ball + SO4, 1.f / P2_);

  // assemble xcat from raw maxes with BN+lrelu
  k_xcat<<<P1_ * 128 / 256, 256, 0, stream>>>(xr1, xr2, xr3, xr4, Aall, Ball, xcat);

  // layer 5: xcat x w5 -> h5 + stats ; 8 k-panels/block
  k_gemm<512, 256, 1, 1, false, true, false, true, false><<<dim3(4, 64), 256, 0, stream>>>(
      xcat, wbb + WO5, b5, nullptr, nullptr, part, h5, nullptr);
  k_bnab<<<4, 256, 0, stream>>>(part, 256, g5, be5, Aall + SO5, Ball + SO5, 1.f / P1_);

  // layer 6: act(h5) x w6 -> h6 + stats
  k_gemm<256, 1024, 2, 2, true, true, false, true, false><<<dim3(8, 32), 256, 0, stream>>>(
      h5, wbb + WO6, b6, Aall + SO5, Ball + SO5, part, h6, nullptr);
  k_bnab<<<16, 256, 0, stream>>>(part, 128, g6, be6, Aall + SO6, Ball + SO6, 1.f / P1_);
  k_apply_out<<<P1_ * 256 / 256, 256, 0, stream>>>(h6, Aall + SO6, Ball + SO6, out);

  (void)in_sizes; (void)n_in; (void)out_size; (void)ws_size;
}